// Round 16
// baseline (395.626 us; speedup 1.0000x reference)
//
#include <hip/hip_runtime.h>
#include <stdint.h>

#define T_SEQ 8192
#define DMODEL 512
#define QKV_LD 1536   // row stride (elements) of fused QKV output

typedef __attribute__((ext_vector_type(8))) short bfx8;     // 8 bf16 = 4 VGPR
typedef __attribute__((ext_vector_type(4))) short bfx4;     // 4 bf16 = 2 VGPR
typedef __attribute__((ext_vector_type(4))) float fx4;      // 16x16 MFMA acc
typedef __attribute__((ext_vector_type(16))) float f32x16;  // 32x32 MFMA acc

__device__ __forceinline__ unsigned short f2bf(float f) {
    uint32_t u = __float_as_uint(f);
    u += 0x7fffu + ((u >> 16) & 1u);     // round-to-nearest-even (inf-safe)
    return (unsigned short)(u >> 16);
}
__device__ __forceinline__ float bf2f(unsigned short s) {
    return __uint_as_float(((uint32_t)s) << 16);
}

// async global->LDS, 16B per lane; LDS dest is wave-uniform base + lane*16 (HW)
__device__ __forceinline__ void gload16(const void* g, void* l) {
    __builtin_amdgcn_global_load_lds(
        (const __attribute__((address_space(1))) unsigned int*)g,
        (__attribute__((address_space(3))) unsigned int*)l,
        16, 0, 0);
}

__device__ __forceinline__ void fence_barrier() {
    asm volatile("" ::: "memory");
    __builtin_amdgcn_s_barrier();
    asm volatile("" ::: "memory");
}

// ---------------- weight conversion f32 -> bf16, all 4 weights in one launch ----------------
__global__ __launch_bounds__(256) void cvt4_bf16_kernel(const float* __restrict__ w0,
                                                        const float* __restrict__ w1,
                                                        const float* __restrict__ w2,
                                                        const float* __restrict__ w3,
                                                        unsigned short* __restrict__ dst) {
    int i = (blockIdx.x * 256 + threadIdx.x) * 8;          // 0 .. 4*262144-1
    int sel = i >> 18;                                     // 262144 elems per weight
    int off = i & 0x3FFFF;
    const float* src = (sel == 0) ? w0 : (sel == 1) ? w1 : (sel == 2) ? w2 : w3;
    fx4 a = *(const fx4*)(src + off);
    fx4 b = *(const fx4*)(src + off + 4);
    bfx8 o;
    o[0] = f2bf(a[0]); o[1] = f2bf(a[1]); o[2] = f2bf(a[2]); o[3] = f2bf(a[3]);
    o[4] = f2bf(b[0]); o[5] = f2bf(b[1]); o[6] = f2bf(b[2]); o[7] = f2bf(b[3]);
    *(bfx8*)(dst + i) = o;
}

// ---------------- LayerNorm (one wave per row) ----------------
__global__ __launch_bounds__(256) void layernorm_kernel(const float* __restrict__ h,
                                                        const float* __restrict__ w,
                                                        const float* __restrict__ b,
                                                        unsigned short* __restrict__ out) {
    int wv = threadIdx.x >> 6, lane = threadIdx.x & 63;
    int row = blockIdx.x * 4 + wv;
    const float* hr = h + (size_t)row * DMODEL + lane * 8;
    fx4 x0 = *(const fx4*)hr;
    fx4 x1 = *(const fx4*)(hr + 4);
    float s  = x0[0]+x0[1]+x0[2]+x0[3]+x1[0]+x1[1]+x1[2]+x1[3];
    float ss = x0[0]*x0[0]+x0[1]*x0[1]+x0[2]*x0[2]+x0[3]*x0[3]
             + x1[0]*x1[0]+x1[1]*x1[1]+x1[2]*x1[2]+x1[3]*x1[3];
    #pragma unroll
    for (int m = 1; m < 64; m <<= 1) { s += __shfl_xor(s, m); ss += __shfl_xor(ss, m); }
    float mu  = s * (1.0f / DMODEL);
    float var = ss * (1.0f / DMODEL) - mu * mu;
    float r = rsqrtf(var + 1e-5f);
    const float* wp = w + lane * 8; const float* bp = b + lane * 8;
    fx4 w0 = *(const fx4*)wp, w1 = *(const fx4*)(wp + 4);
    fx4 b0 = *(const fx4*)bp, b1 = *(const fx4*)(bp + 4);
    bfx8 o;
    o[0] = f2bf((x0[0]-mu)*r*w0[0] + b0[0]);
    o[1] = f2bf((x0[1]-mu)*r*w0[1] + b0[1]);
    o[2] = f2bf((x0[2]-mu)*r*w0[2] + b0[2]);
    o[3] = f2bf((x0[3]-mu)*r*w0[3] + b0[3]);
    o[4] = f2bf((x1[0]-mu)*r*w1[0] + b1[0]);
    o[5] = f2bf((x1[1]-mu)*r*w1[1] + b1[1]);
    o[6] = f2bf((x1[2]-mu)*r*w1[2] + b1[2]);
    o[7] = f2bf((x1[3]-mu)*r*w1[3] + b1[3]);
    *(bfx8*)(out + (size_t)row * DMODEL + lane * 8) = o;
}

// ---------------- C = A @ B^T  (both [rows][K] bf16), 128x128 tile ----------------
template<int RESID>
__global__ __launch_bounds__(256, 2) void gemm_bt_kernel(
    const unsigned short* __restrict__ A,   // [M][K]
    const unsigned short* __restrict__ B,   // [N][K]
    unsigned short* __restrict__ Cb,
    float* __restrict__ Cf,
    const float* __restrict__ resid,
    int M, int N, int K)
{
    __shared__ unsigned short At[128 * 64];
    __shared__ unsigned short Bt[128 * 64];
    int tid = threadIdx.x;
    int wv = tid >> 6, lane = tid & 63, l15 = lane & 15, l4 = lane >> 4;
    int wr = wv >> 1, wc = wv & 1;
    int row0 = blockIdx.y * 128;
    int col0 = blockIdx.x * 128;
    fx4 acc[4][4] = {};
    const char* Abase = (const char*)(A + (size_t)row0 * K);
    const char* Bbase = (const char*)(B + (size_t)col0 * K);
    for (int kt = 0; kt < K; kt += 64) {
        #pragma unroll
        for (int ch = 0; ch < 4; ch++) {
            int bix = (ch * 256 + tid) * 16;
            int r = bix >> 7;
            int sb = (bix & 127) ^ ((r & 7) << 4);
            bfx8 va = *(const bfx8*)(Abase + (size_t)r * (K * 2) + kt * 2 + sb);
            bfx8 vb = *(const bfx8*)(Bbase + (size_t)r * (K * 2) + kt * 2 + sb);
            *(bfx8*)((char*)At + bix) = va;
            *(bfx8*)((char*)Bt + bix) = vb;
        }
        __syncthreads();
        #pragma unroll
        for (int ks = 0; ks < 2; ks++) {
            bfx8 af[4], bf[4];
            #pragma unroll
            for (int m = 0; m < 4; m++) {
                int ra = wr * 64 + m * 16 + l15;
                int ka = (ks * 64 + l4 * 16) ^ ((ra & 7) << 4);
                af[m] = *(const bfx8*)((const char*)At + ra * 128 + ka);
                int rb = wc * 64 + m * 16 + l15;
                int kb = (ks * 64 + l4 * 16) ^ ((rb & 7) << 4);
                bf[m] = *(const bfx8*)((const char*)Bt + rb * 128 + kb);
            }
            #pragma unroll
            for (int m = 0; m < 4; m++)
                #pragma unroll
                for (int n = 0; n < 4; n++)
                    acc[m][n] = __builtin_amdgcn_mfma_f32_16x16x32_bf16(af[m], bf[n], acc[m][n], 0, 0, 0);
        }
        __syncthreads();
    }
    #pragma unroll
    for (int m = 0; m < 4; m++)
        #pragma unroll
        for (int n = 0; n < 4; n++)
            #pragma unroll
            for (int r = 0; r < 4; r++) {
                int row = row0 + wr * 64 + m * 16 + l4 * 4 + r;
                int col = col0 + wc * 64 + n * 16 + l15;
                float v = acc[m][n][r];
                size_t o = (size_t)row * N + col;
                if (RESID) Cf[o] = v + resid[o];
                else       Cb[o] = f2bf(v);
            }
}

// ---------------- transpose V [T][ld] -> Vt [D][T] ----------------
__global__ __launch_bounds__(256) void transpose_kernel(const unsigned short* __restrict__ v,
                                                        unsigned short* __restrict__ vt, int ld) {
    __shared__ unsigned short tile[64][80];
    int t = threadIdx.x;
    int r0 = blockIdx.x * 64;   // T dim
    int c0 = blockIdx.y * 64;   // D dim
    int r = t >> 2, cw = (t & 3) * 16;
    const unsigned short* src = v + (size_t)(r0 + r) * ld + c0 + cw;
    bfx8 a = *(const bfx8*)src;
    bfx8 b = *(const bfx8*)(src + 8);
    #pragma unroll
    for (int j = 0; j < 8; j++) { tile[r][cw + j] = a[j]; tile[r][cw + 8 + j] = b[j]; }
    __syncthreads();
    int dc = t >> 2, rb = (t & 3) * 16;
    bfx8 o0, o1;
    #pragma unroll
    for (int j = 0; j < 8; j++) { o0[j] = tile[rb + j][dc]; o1[j] = tile[rb + 8 + j][dc]; }
    unsigned short* dst = vt + (size_t)(c0 + dc) * T_SEQ + r0 + rb;
    *(bfx8*)dst = o0;
    *(bfx8*)(dst + 8) = o1;
}

// ---------------- flash attention v16: Q-in-registers + double-buffered K/V,
// counted-vmcnt deep pipeline (T3/T4). Derived from flash15 (R15, 198us).
// 768 threads, 12 waves. QBLK=64, KVBLK=32.
// Waves 0-3 (S): Q in regs as swapped-MFMA B-operand (qf[16]=64 VGPR); QK^T(t)
//   reads ONLY K from LDS (16 ds_read + 16 MFMA chain); softmax in phase B.
// Waves 4-11 (O, acc 64 AGPR): rescale+PV(t-1); ALL staging (K and V).
// K_lds[2]/V_lds[2] double buffers (Q freed 64KB): stage K(t+2)/V(t+1) at
// phase B(t) -> a full iteration to land. B1 waits COUNTED vmcnt(8) (4/0 at
// tail) -> loads stay in flight across barriers; staging latency off the
// critical path. LDS: K 64 + V 64 + Sp 8 + P 4 = 140.3KB, 1 WG/CU.
// V/P macro-row pairing swizzle kept from flash15 (2-way banks).
// Spill tripwire: WRITE_SIZE >> 70MB => revert.
__global__ __launch_bounds__(768)
void flash16_kernel(
    const unsigned short* __restrict__ q,      // rows stride QKV_LD
    const unsigned short* __restrict__ k,      // rows stride QKV_LD
    const unsigned short* __restrict__ vt,     // [DMODEL][T_SEQ]
    unsigned short* __restrict__ opart,        // [NBLK][64][512] bf16 unnormalized
    float* __restrict__ mbuf, float* __restrict__ lbuf,   // [NBLK][64]
    int CH, int NBLK)                          // CH = kv chunks of 64-row units
{
    __shared__ unsigned short K_lds[2][32 * 512];  // 2x32KB, rows 1024B
    __shared__ unsigned short V_lds[2][512 * 32];  // 2x32KB, 256 macro-rows of 128B
    __shared__ unsigned short Sp_lds[2 * 64 * 32]; // 8KB partial S bf16, rows 64B
    __shared__ unsigned short p_lds[64 * 32];      // 4KB, 32 macro-rows of 128B
    __shared__ float alpha_lds[64];

    int tid = threadIdx.x;
    int wv = tid >> 6, lane = tid & 63, l15 = lane & 15, l4 = lane >> 4;
    int l31 = lane & 31, hi = lane >> 5;
    bool isS = wv < 4;

    // XCD-chunked bijective swizzle (NBLK % 8 == 0)
    int L = blockIdx.x;
    int bid = (L & 7) * (NBLK >> 3) + (L >> 3);

    // chunk-major decode (128 q-tiles of 64 rows): cum(c) = 128c - CH*c*(c-1)/2
    int c = 0;
    while (bid >= 128 * (c + 1) - CH * (c + 1) * c / 2) c++;
    int qi = CH * c + (bid - (128 * c - CH * c * (c - 1) / 2));
    int R0 = qi * 64;
    int kv_begin = c * CH * 64;
    int kv_end = min(kv_begin + CH * 64, R0 + 64);
    int ntile = (kv_end - kv_begin) >> 5;       // 32-row kv tiles

    int qg = wv >> 1, kb = wv & 1;              // S roles (wv 0..3)
    int ro = (wv - 4) >> 2, co = (wv - 4) & 3;  // O roles (wv 4..11)

    const float rscale = 0.044194173824159216f; // 1/sqrt(512)

    float m_run = -INFINITY, l_run = 0.f;
    int srow = wv * 16 + (lane >> 2);           // S-wave softmax row (wv<4)
    fx4 acc[2][8] = {};                         // O-wave accumulator (AGPR)

    // S-wave Q fragments (swapped-MFMA B-operand):
    // qrow = R0 + qg*32 + l31 ; per MFMA ks: k = kb*256 + ks*16 + hi*8 + j
    bfx8 qf[16];
    if (isS) {
        const unsigned short* qp = q + (size_t)(R0 + qg * 32 + l31) * QKV_LD + kb * 256 + hi * 8;
        #pragma unroll
        for (int ks = 0; ks < 16; ks++) qf[ks] = *(const bfx8*)(qp + ks * 16);
    }

    // ---- staging (O-waves only), tile index t2 -> buffer t2&1 ----
    auto stageK = [&](int t2) {
        if (wv < 4) return;
        const char* kbp = (const char*)k + ((size_t)kv_begin + (size_t)t2 * 32) * (QKV_LD * 2);
        #pragma unroll
        for (int j = 0; j < 4; j++) {
            int krow = (wv - 4) * 4 + j;
            const char* gp = kbp + (size_t)krow * (QKV_LD * 2) + ((lane * 16) ^ ((krow & 15) << 4));
            gload16(gp, (char*)K_lds[t2 & 1] + krow * 1024);
        }
    };
    auto stageV = [&](int t2) {
        if (wv < 4) return;
        const char* vb = (const char*)vt + ((size_t)kv_begin + (size_t)t2 * 32) * 2;
        #pragma unroll
        for (int j = 0; j < 4; j++) {
            int seg = (wv - 4) * 4 + j;
            int r = seg * 8 + (lane >> 3);      // 128B macro-row (= d>>1)
            int pg = lane & 7;
            int lg = pg ^ (r & 7);              // logical granule
            int d = 2 * r + ((lg >> 2) & 1);    // V d-row
            int ch2 = lg & 3;                   // kv 16B chunk
            const char* gp = vb + (size_t)d * (T_SEQ * 2) + ch2 * 16;
            gload16(gp, (char*)V_lds[t2 & 1] + seg * 1024);
        }
    };

    // prologue: K(0), K(1), V(0)
    stageK(0);
    if (ntile > 1) stageK(1);
    stageV(0);

    for (int t = 0; t <= ntile; t++) {
        int kv0 = kv_begin + t * 32;

        // counted waits: allow the loads issued at the previous stage slot to
        // stay in flight (K(t+1): 4, V(t): 4); drain everything older.
        if (t == ntile)          asm volatile("s_waitcnt vmcnt(0)" ::: "memory");
        else if (t + 1 == ntile) asm volatile("s_waitcnt vmcnt(4)" ::: "memory");
        else                     asm volatile("s_waitcnt vmcnt(8)" ::: "memory");
        fence_barrier();                        // B1: K(t), V(t-1), P/alpha(t-1) ready
        __builtin_amdgcn_sched_barrier(0);

        // ================= PHASE A =================
        if (isS) {
            if (t < ntile) {
                // swapped QK^T: D[kv][q] = K x Q^T over k-half kb; Q from regs
                f32x16 sacc = {};
                int ksw = (l31 & 15) << 4;                 // K row = l31
                const char* kbase2 = (const char*)K_lds[t & 1] + l31 * 1024;
                #pragma unroll
                for (int ks = 0; ks < 16; ks++) {
                    bfx8 kfr = *(const bfx8*)(kbase2 + ((kb * 512 + ks * 32 + hi * 16) ^ ksw));
                    sacc = __builtin_amdgcn_mfma_f32_32x32x16_bf16(kfr, qf[ks], sacc, 0, 0, 0);
                }
                // scale + causal mask -> bf16 Sp[kb][qrow][kv]
                int qrow = qg * 32 + l31;
                char* spb = (char*)Sp_lds + kb * 4096 + qrow * 64;
                int spsw = (qrow & 3) << 4;
                #pragma unroll
                for (int a = 0; a < 4; a++) {
                    bfx4 ch;
                    #pragma unroll
                    for (int b = 0; b < 4; b++) {
                        int r = a * 4 + b;
                        int kvloc = b + 8 * a + 4 * hi;    // m74/m101 C-layout
                        float x = sacc[r] * rscale;
                        if (kv0 + kvloc > R0 + qrow) x = -INFINITY;
                        ch[b] = (short)f2bf(x);
                    }
                    *(bfx4*)(spb + ((a * 16 + hi * 8) ^ spsw)) = ch;
                }
            }
        } else {
            if (t > 0) {
                // rescale by alpha(t-1) (skipped when all alpha==1), then PV(t-1)
                fx4 apv[2];
                apv[0] = *(const fx4*)&alpha_lds[ro * 32 + l4 * 4];
                apv[1] = *(const fx4*)&alpha_lds[ro * 32 + 16 + l4 * 4];
                bool need = !(apv[0][0] == 1.f && apv[0][1] == 1.f && apv[0][2] == 1.f && apv[0][3] == 1.f
                           && apv[1][0] == 1.f && apv[1][1] == 1.f && apv[1][2] == 1.f && apv[1][3] == 1.f);
                if (__any(need)) {
                    #pragma unroll
                    for (int m = 0; m < 2; m++)
                        #pragma unroll
                        for (int n = 0; n < 8; n++)
                            #pragma unroll
                            for (int r = 0; r < 4; r++)
                                acc[m][n][r] *= apv[m][r];
                }
                bfx8 pa[2];
                #pragma unroll
                for (int m = 0; m < 2; m++) {
                    int prow = ro * 32 + m * 16 + l15;
                    int pr = prow >> 1;
                    int ppg = (((prow & 1) << 2) | l4) ^ (pr & 7);
                    pa[m] = *(const bfx8*)((const char*)p_lds + pr * 128 + ppg * 16);
                }
                const char* vbuf = (const char*)V_lds[(t - 1) & 1];
                #pragma unroll
                for (int n = 0; n < 8; n++) {
                    int d = co * 128 + n * 16 + l15;
                    int vr = d >> 1;
                    int vpg = (((d & 1) << 2) | l4) ^ (vr & 7);
                    bfx8 vfr = *(const bfx8*)(vbuf + vr * 128 + vpg * 16);
                    acc[0][n] = __builtin_amdgcn_mfma_f32_16x16x32_bf16(pa[0], vfr, acc[0][n], 0, 0, 0);
                    acc[1][n] = __builtin_amdgcn_mfma_f32_16x16x32_bf16(pa[1], vfr, acc[1][n], 0, 0, 0);
                }
            }
        }
        if (t == ntile) break;

        asm volatile("s_waitcnt lgkmcnt(0)" ::: "memory");
        fence_barrier();                        // B2: Sp complete; K(t)/V(t-1)/P reads done
        __builtin_amdgcn_sched_barrier(0);

        // deep-pipeline staging: K(t+2) into buf[t&1] (K(t) reads done),
        // V(t+1) into buf[(t+1)&1] (V(t-1) reads done). A full iter to land.
        if (t + 2 < ntile) stageK(t + 2);
        if (t + 1 < ntile) stageV(t + 1);

        // ================= PHASE B: softmax(t) on S-waves =================
        if (isS) {
            int soff = srow * 64 + (((lane & 3) * 16) ^ ((srow & 3) << 4));
            bfx8 s0 = *(const bfx8*)((const char*)Sp_lds + soff);
            bfx8 s1 = *(const bfx8*)((const char*)Sp_lds + 4096 + soff);
            float xv[8];
            float mx = -INFINITY;
            #pragma unroll
            for (int j = 0; j < 8; j++) {
                xv[j] = bf2f((unsigned short)s0[j]) + bf2f((unsigned short)s1[j]);
                mx = fmaxf(mx, xv[j]);
            }
            mx = fmaxf(mx, __shfl_xor(mx, 1));
            mx = fmaxf(mx, __shfl_xor(mx, 2));
            float al;
            if (__all(mx <= m_run)) {
                al = 1.f;                                   // defer-max: no new max anywhere
            } else {
                float mn = fmaxf(m_run, mx);
                float msafe = (mn == -INFINITY) ? 0.f : mn;
                al = __expf(m_run - msafe);                 // m_run=-inf -> 0
                m_run = mn;
            }
            float msafe2 = (m_run == -INFINITY) ? 0.f : m_run;
            if ((lane & 3) == 0) alpha_lds[srow] = al;
            float ps = 0.f;
            bfx8 pw;
            #pragma unroll
            for (int j = 0; j < 8; j++) {
                float p = __expf(xv[j] - msafe2);           // -inf -> 0
                pw[j] = (short)f2bf(p);
                ps += p;
            }
            // paired-row P write: row srow, chunk lane&3
            {
                int pr = srow >> 1;
                int ppg = (((srow & 1) << 2) | (lane & 3)) ^ (pr & 7);
                *(bfx8*)((char*)p_lds + pr * 128 + ppg * 16) = pw;
            }
            ps += __shfl_xor(ps, 1);
            ps += __shfl_xor(ps, 2);
            l_run = l_run * al + ps;
        }
    }

    // ---- epilogue ----
    if (!isS) {
        #pragma unroll
        for (int m = 0; m < 2; m++)
            #pragma unroll
            for (int n = 0; n < 8; n++)
                #pragma unroll
                for (int r = 0; r < 4; r++) {
                    int rowl = ro * 32 + m * 16 + l4 * 4 + r;
                    int col = co * 128 + n * 16 + l15;
                    opart[((size_t)bid * 64 + rowl) * DMODEL + col] = f2bf(acc[m][n][r]);
                }
    } else if ((lane & 3) == 0) {
        mbuf[(size_t)bid * 64 + srow] = m_run;
        lbuf[(size_t)bid * 64 + srow] = l_run;
    }
}

// ---------------- combine partials across KV chunks ----------------
__global__ __launch_bounds__(256) void combine2_kernel(
    const unsigned short* __restrict__ opart,
    const float* __restrict__ mbuf, const float* __restrict__ lbuf,
    unsigned short* __restrict__ attn, int CH)
{
    int tid = threadIdx.x;
    int row = blockIdx.x * 4 + (tid >> 6);
    int col = (tid & 63) * 8;
    int qi = row >> 6, rowl = row & 63;
    int nch = qi / CH + 1;
    float M = -INFINITY;
    for (int c = 0; c < nch; c++) {
        int pidx = 128 * c - CH * c * (c - 1) / 2 + (qi - CH * c);
        M = fmaxf(M, mbuf[(size_t)pidx * 64 + rowl]);
    }
    float L = 0.f;
    float accv[8] = {0.f,0.f,0.f,0.f,0.f,0.f,0.f,0.f};
    for (int c = 0; c < nch; c++) {
        int pidx = 128 * c - CH * c * (c - 1) / 2 + (qi - CH * c);
        float e = __expf(mbuf[(size_t)pidx * 64 + rowl] - M);
        L += lbuf[(size_t)pidx * 64 + rowl] * e;
        bfx8 v = *(const bfx8*)(opart + ((size_t)pidx * 64 + rowl) * DMODEL + col);
        #pragma unroll
        for (int j = 0; j < 8; j++) accv[j] += e * bf2f((unsigned short)v[j]);
    }
    float invL = 1.0f / L;
    bfx8 o;
    #pragma unroll
    for (int j = 0; j < 8; j++) o[j] = f2bf(accv[j] * invL);
    *(bfx8*)(attn + (size_t)row * DMODEL + col) = o;
}

// ---------------- host launcher ----------------
extern "C" void kernel_launch(void* const* d_in, const int* in_sizes, int n_in,
                              void* d_out, int out_size, void* d_ws, size_t ws_size,
                              hipStream_t stream) {
    const float* h   = (const float*)d_in[0];
    const float* lnw = (const float*)d_in[1];
    const float* lnb = (const float*)d_in[2];
    const float* wq  = (const float*)d_in[3];
    const float* wk  = (const float*)d_in[4];
    const float* wv  = (const float*)d_in[5];
    const float* wo  = (const float*)d_in[6];
    float* out = (float*)d_out;

    char* ws = (char*)d_ws;
    size_t off = 0;
    auto alloc = [&](size_t bytes) {
        char* p = ws + off;
        off += (bytes + 255) & ~(size_t)255;
        return p;
    };
    const size_t TD2 = (size_t)T_SEQ * DMODEL * 2;
    const size_t W2  = (size_t)DMODEL * DMODEL * 2;
    unsigned short* hn   = (unsigned short*)alloc(TD2);
    unsigned short* wall = (unsigned short*)alloc(4 * W2);   // [wq;wk;wv;wo] contiguous
    unsigned short* wqkv = wall;
    unsigned short* wob  = wall + 3 * DMODEL * DMODEL;
    unsigned short* qkvb = (unsigned short*)alloc((size_t)T_SEQ * QKV_LD * 2);  // fused QKV
    unsigned short* vtb  = (unsigned short*)alloc(TD2);
    unsigned short* attnb= (unsigned short*)alloc(TD2);

    // KV chunking: CH kv-units (64 rows each) per chunk; NBLK = sum ceil((qi+1)/CH)
    int CH = 8, NBLK = 1088;     // 8*(1+..+16) = 1088, %8==0
    {
        size_t need = off + 2 * ((1088u * 64 * 4 + 255) & ~(size_t)255)
                    + (((size_t)1088 * 64 * 512 * 2 + 255) & ~(size_t)255);
        if (need > ws_size) { CH = 16; NBLK = 576; }   // 16*(1+..+8)=576, %8==0
    }
    float* mbuf = (float*)alloc((size_t)NBLK * 64 * 4);
    float* lbuf = (float*)alloc((size_t)NBLK * 64 * 4);
    unsigned short* opart = (unsigned short*)alloc((size_t)NBLK * 64 * 512 * 2);

    cvt4_bf16_kernel<<<dim3(512), dim3(256), 0, stream>>>(wq, wk, wv, wo, wall);

    layernorm_kernel<<<dim3(T_SEQ / 4), dim3(256), 0, stream>>>(h, lnw, lnb, hn);

    // fused QKV projection: [T,512] @ [1536,512]^T -> [T,1536]
    gemm_bt_kernel<0><<<dim3(QKV_LD / 128, T_SEQ / 128), dim3(256), 0, stream>>>(
        hn, wqkv, qkvb, nullptr, nullptr, T_SEQ, QKV_LD, DMODEL);

    // V (cols 1024..1535 of qkvb) -> Vt [512][T]
    transpose_kernel<<<dim3(T_SEQ / 64, DMODEL / 64), dim3(256), 0, stream>>>(
        qkvb + 2 * DMODEL, vtb, QKV_LD);

    flash16_kernel<<<dim3(NBLK), dim3(768), 0, stream>>>(
        qkvb, qkvb + DMODEL, vtb, opart, mbuf, lbuf, CH, NBLK);

    combine2_kernel<<<dim3(T_SEQ / 4), dim3(256), 0, stream>>>(opart, mbuf, lbuf, attnb, CH);

    gemm_bt_kernel<1><<<dim3(DMODEL / 128, T_SEQ / 128), dim3(256), 0, stream>>>(
        attnb, wob, nullptr, out, h, T_SEQ, DMODEL, DMODEL);
}

// Round 17
// 271.850 us; speedup vs baseline: 1.4553x; 1.4553x over previous
//
#include <hip/hip_runtime.h>
#include <stdint.h>

#define T_SEQ 8192
#define DMODEL 512
#define QKV_LD 1536   // row stride (elements) of fused QKV output

typedef __attribute__((ext_vector_type(8))) short bfx8;     // 8 bf16 = 4 VGPR
typedef __attribute__((ext_vector_type(4))) short bfx4;     // 4 bf16 = 2 VGPR
typedef __attribute__((ext_vector_type(4))) float fx4;      // 16x16 MFMA acc
typedef __attribute__((ext_vector_type(16))) float f32x16;  // 32x32 MFMA acc

__device__ __forceinline__ unsigned short f2bf(float f) {
    uint32_t u = __float_as_uint(f);
    u += 0x7fffu + ((u >> 16) & 1u);     // round-to-nearest-even (inf-safe)
    return (unsigned short)(u >> 16);
}
__device__ __forceinline__ float bf2f(unsigned short s) {
    return __uint_as_float(((uint32_t)s) << 16);
}

// async global->LDS, 16B per lane; LDS dest is wave-uniform base + lane*16 (HW)
__device__ __forceinline__ void gload16(const void* g, void* l) {
    __builtin_amdgcn_global_load_lds(
        (const __attribute__((address_space(1))) unsigned int*)g,
        (__attribute__((address_space(3))) unsigned int*)l,
        16, 0, 0);
}

__device__ __forceinline__ void fence_barrier() {
    asm volatile("" ::: "memory");
    __builtin_amdgcn_s_barrier();
    asm volatile("" ::: "memory");
}

// ---------------- weight conversion f32 -> bf16, all 4 weights in one launch ----------------
__global__ __launch_bounds__(256) void cvt4_bf16_kernel(const float* __restrict__ w0,
                                                        const float* __restrict__ w1,
                                                        const float* __restrict__ w2,
                                                        const float* __restrict__ w3,
                                                        unsigned short* __restrict__ dst) {
    int i = (blockIdx.x * 256 + threadIdx.x) * 8;          // 0 .. 4*262144-1
    int sel = i >> 18;                                     // 262144 elems per weight
    int off = i & 0x3FFFF;
    const float* src = (sel == 0) ? w0 : (sel == 1) ? w1 : (sel == 2) ? w2 : w3;
    fx4 a = *(const fx4*)(src + off);
    fx4 b = *(const fx4*)(src + off + 4);
    bfx8 o;
    o[0] = f2bf(a[0]); o[1] = f2bf(a[1]); o[2] = f2bf(a[2]); o[3] = f2bf(a[3]);
    o[4] = f2bf(b[0]); o[5] = f2bf(b[1]); o[6] = f2bf(b[2]); o[7] = f2bf(b[3]);
    *(bfx8*)(dst + i) = o;
}

// ---------------- LayerNorm (one wave per row) ----------------
__global__ __launch_bounds__(256) void layernorm_kernel(const float* __restrict__ h,
                                                        const float* __restrict__ w,
                                                        const float* __restrict__ b,
                                                        unsigned short* __restrict__ out) {
    int wv = threadIdx.x >> 6, lane = threadIdx.x & 63;
    int row = blockIdx.x * 4 + wv;
    const float* hr = h + (size_t)row * DMODEL + lane * 8;
    fx4 x0 = *(const fx4*)hr;
    fx4 x1 = *(const fx4*)(hr + 4);
    float s  = x0[0]+x0[1]+x0[2]+x0[3]+x1[0]+x1[1]+x1[2]+x1[3];
    float ss = x0[0]*x0[0]+x0[1]*x0[1]+x0[2]*x0[2]+x0[3]*x0[3]
             + x1[0]*x1[0]+x1[1]*x1[1]+x1[2]*x1[2]+x1[3]*x1[3];
    #pragma unroll
    for (int m = 1; m < 64; m <<= 1) { s += __shfl_xor(s, m); ss += __shfl_xor(ss, m); }
    float mu  = s * (1.0f / DMODEL);
    float var = ss * (1.0f / DMODEL) - mu * mu;
    float r = rsqrtf(var + 1e-5f);
    const float* wp = w + lane * 8; const float* bp = b + lane * 8;
    fx4 w0 = *(const fx4*)wp, w1 = *(const fx4*)(wp + 4);
    fx4 b0 = *(const fx4*)bp, b1 = *(const fx4*)(bp + 4);
    bfx8 o;
    o[0] = f2bf((x0[0]-mu)*r*w0[0] + b0[0]);
    o[1] = f2bf((x0[1]-mu)*r*w0[1] + b0[1]);
    o[2] = f2bf((x0[2]-mu)*r*w0[2] + b0[2]);
    o[3] = f2bf((x0[3]-mu)*r*w0[3] + b0[3]);
    o[4] = f2bf((x1[0]-mu)*r*w1[0] + b1[0]);
    o[5] = f2bf((x1[1]-mu)*r*w1[1] + b1[1]);
    o[6] = f2bf((x1[2]-mu)*r*w1[2] + b1[2]);
    o[7] = f2bf((x1[3]-mu)*r*w1[3] + b1[3]);
    *(bfx8*)(out + (size_t)row * DMODEL + lane * 8) = o;
}

// ---------------- C = A @ B^T  (both [rows][K] bf16), 128x128 tile ----------------
template<int RESID>
__global__ __launch_bounds__(256, 2) void gemm_bt_kernel(
    const unsigned short* __restrict__ A,   // [M][K]
    const unsigned short* __restrict__ B,   // [N][K]
    unsigned short* __restrict__ Cb,
    float* __restrict__ Cf,
    const float* __restrict__ resid,
    int M, int N, int K)
{
    __shared__ unsigned short At[128 * 64];
    __shared__ unsigned short Bt[128 * 64];
    int tid = threadIdx.x;
    int wv = tid >> 6, lane = tid & 63, l15 = lane & 15, l4 = lane >> 4;
    int wr = wv >> 1, wc = wv & 1;
    int row0 = blockIdx.y * 128;
    int col0 = blockIdx.x * 128;
    fx4 acc[4][4] = {};
    const char* Abase = (const char*)(A + (size_t)row0 * K);
    const char* Bbase = (const char*)(B + (size_t)col0 * K);
    for (int kt = 0; kt < K; kt += 64) {
        #pragma unroll
        for (int ch = 0; ch < 4; ch++) {
            int bix = (ch * 256 + tid) * 16;
            int r = bix >> 7;
            int sb = (bix & 127) ^ ((r & 7) << 4);
            bfx8 va = *(const bfx8*)(Abase + (size_t)r * (K * 2) + kt * 2 + sb);
            bfx8 vb = *(const bfx8*)(Bbase + (size_t)r * (K * 2) + kt * 2 + sb);
            *(bfx8*)((char*)At + bix) = va;
            *(bfx8*)((char*)Bt + bix) = vb;
        }
        __syncthreads();
        #pragma unroll
        for (int ks = 0; ks < 2; ks++) {
            bfx8 af[4], bf[4];
            #pragma unroll
            for (int m = 0; m < 4; m++) {
                int ra = wr * 64 + m * 16 + l15;
                int ka = (ks * 64 + l4 * 16) ^ ((ra & 7) << 4);
                af[m] = *(const bfx8*)((const char*)At + ra * 128 + ka);
                int rb = wc * 64 + m * 16 + l15;
                int kb = (ks * 64 + l4 * 16) ^ ((rb & 7) << 4);
                bf[m] = *(const bfx8*)((const char*)Bt + rb * 128 + kb);
            }
            #pragma unroll
            for (int m = 0; m < 4; m++)
                #pragma unroll
                for (int n = 0; n < 4; n++)
                    acc[m][n] = __builtin_amdgcn_mfma_f32_16x16x32_bf16(af[m], bf[n], acc[m][n], 0, 0, 0);
        }
        __syncthreads();
    }
    #pragma unroll
    for (int m = 0; m < 4; m++)
        #pragma unroll
        for (int n = 0; n < 4; n++)
            #pragma unroll
            for (int r = 0; r < 4; r++) {
                int row = row0 + wr * 64 + m * 16 + l4 * 4 + r;
                int col = col0 + wc * 64 + n * 16 + l15;
                float v = acc[m][n][r];
                size_t o = (size_t)row * N + col;
                if (RESID) Cf[o] = v + resid[o];
                else       Cb[o] = f2bf(v);
            }
}

// ---------------- transpose V [T][ld] -> Vt [D][T] ----------------
__global__ __launch_bounds__(256) void transpose_kernel(const unsigned short* __restrict__ v,
                                                        unsigned short* __restrict__ vt, int ld) {
    __shared__ unsigned short tile[64][80];
    int t = threadIdx.x;
    int r0 = blockIdx.x * 64;   // T dim
    int c0 = blockIdx.y * 64;   // D dim
    int r = t >> 2, cw = (t & 3) * 16;
    const unsigned short* src = v + (size_t)(r0 + r) * ld + c0 + cw;
    bfx8 a = *(const bfx8*)src;
    bfx8 b = *(const bfx8*)(src + 8);
    #pragma unroll
    for (int j = 0; j < 8; j++) { tile[r][cw + j] = a[j]; tile[r][cw + 8 + j] = b[j]; }
    __syncthreads();
    int dc = t >> 2, rb = (t & 3) * 16;
    bfx8 o0, o1;
    #pragma unroll
    for (int j = 0; j < 8; j++) { o0[j] = tile[rb + j][dc]; o1[j] = tile[rb + 8 + j][dc]; }
    unsigned short* dst = vt + (size_t)(c0 + dc) * T_SEQ + r0 + rb;
    *(bfx8*)dst = o0;
    *(bfx8*)(dst + 8) = o1;
}

// ---------------- flash attention v17: flash15 (R15 anchor, 198us flash / 251 total)
// + 2-way independent sacc chains in QK^T (halves the 16-deep dependent 32x32-MFMA
// latency chain on the S-wave critical path; +16 AGPR on S-waves only, no arch-reg
// change -> no spill risk). R16's Q-in-reg deep pipeline reverted (spilled, 294MB).
// 768 threads, 12 waves. QBLK=64, KVBLK=32.
// Waves 0-3 (S): swapped 32x32 QK^T k-split -> Sp bf16 -> softmax (phase B).
// Waves 4-11 (O, acc 64 AGPR): rescale+PV(t-1) in phase A, concurrent with QK^T(t).
// V/P macro-row pairing swizzle (2-way banks), strength-reduced staging, defer-max.
__global__ __launch_bounds__(768)
void flash17_kernel(
    const unsigned short* __restrict__ q,      // rows stride QKV_LD
    const unsigned short* __restrict__ k,      // rows stride QKV_LD
    const unsigned short* __restrict__ vt,     // [DMODEL][T_SEQ]
    unsigned short* __restrict__ opart,        // [NBLK][64][512] bf16 unnormalized
    float* __restrict__ mbuf, float* __restrict__ lbuf,   // [NBLK][64]
    int CH, int NBLK)                          // CH = kv chunks of 64-row units
{
    __shared__ unsigned short Q_lds[64 * 512];     // 64KB, rows 1024B
    __shared__ unsigned short K_lds[32 * 512];     // 32KB, rows 1024B
    __shared__ unsigned short V_lds[512 * 32];     // 32KB, 256 macro-rows of 128B
    __shared__ unsigned short Sp_lds[2 * 64 * 32]; // 8KB partial S bf16, rows 64B
    __shared__ unsigned short p_lds[64 * 32];      // 4KB, 32 macro-rows of 128B
    __shared__ float alpha_lds[64];

    int tid = threadIdx.x;
    int wv = tid >> 6, lane = tid & 63, l15 = lane & 15, l4 = lane >> 4;
    int l31 = lane & 31, hi = lane >> 5;
    bool isS = wv < 4;

    // XCD-chunked bijective swizzle (NBLK % 8 == 0)
    int L = blockIdx.x;
    int bid = (L & 7) * (NBLK >> 3) + (L >> 3);

    // chunk-major decode (128 q-tiles of 64 rows): cum(c) = 128c - CH*c*(c-1)/2
    int c = 0;
    while (bid >= 128 * (c + 1) - CH * (c + 1) * c / 2) c++;
    int qi = CH * c + (bid - (128 * c - CH * c * (c - 1) / 2));
    int R0 = qi * 64;
    int kv_begin = c * CH * 64;
    int kv_end = min(kv_begin + CH * 64, R0 + 64);
    int ntile = (kv_end - kv_begin) >> 5;       // 32-row kv tiles

    int qg = wv >> 1, kb = wv & 1;              // S roles (wv 0..3)
    int ro = (wv - 4) >> 2, co = (wv - 4) & 3;  // O roles (wv 4..11)

    const float rscale = 0.044194173824159216f; // 1/sqrt(512)

    float m_run = -INFINITY, l_run = 0.f;
    int srow = wv * 16 + (lane >> 2);           // S-wave softmax row (wv<4)
    fx4 acc[2][8] = {};                         // O-wave accumulator (AGPR)

    // ---- precomputed per-lane staging offsets (loop-invariant) ----
    uint32_t koff[4], voff[4];                  // K: waves 0-7; V: waves 4-11
    {
        #pragma unroll
        for (int j = 0; j < 4; j++) {
            int krow = wv * 4 + j;              // valid for wv<8
            koff[j] = (uint32_t)krow * (QKV_LD * 2) + ((lane * 16) ^ ((krow & 15) << 4));
            // V pairing: LDS byte = seg*1024 + lane*16; macro-row r, phys granule pg
            int seg = (wv - 4) * 4 + j;         // valid for wv>=4
            int r = seg * 8 + (lane >> 3);      // 128B macro-row (= d>>1)
            int pg = lane & 7;
            int lg = pg ^ (r & 7);              // logical granule
            int d = 2 * r + ((lg >> 2) & 1);    // V d-row
            int ch = lg & 3;                    // kv 16B chunk
            voff[j] = (uint32_t)d * (T_SEQ * 2) + ch * 16;
        }
    }
    const char* kbase = (const char*)k + (size_t)kv_begin * (QKV_LD * 2);  // advances 32 rows/iter
    const char* vbase = (const char*)vt + (size_t)kv_begin * 2;            // advances 64 B/iter

    auto stageQ = [&]() {
        if (wv >= 8) return;
        const char* qb = (const char*)q + (size_t)R0 * (QKV_LD * 2);
        #pragma unroll
        for (int j = 0; j < 8; j++) {
            int row = wv * 8 + j;
            const char* gp = qb + (size_t)row * (QKV_LD * 2)
                           + ((lane * 16) ^ ((row & 15) << 4));
            gload16(gp, (char*)Q_lds + row * 1024);
        }
    };
    auto stageK2 = [&](const char* kb2) {
        if (wv >= 8) return;                    // waves 0-7: 4 rows each
        #pragma unroll
        for (int j = 0; j < 4; j++)
            gload16(kb2 + koff[j], (char*)K_lds + (wv * 4 + j) * 1024);
    };
    auto stageV2 = [&](const char* vb2) {
        if (wv < 4) return;                     // waves 4-11: 4 segs each
        #pragma unroll
        for (int j = 0; j < 4; j++)
            gload16(vb2 + voff[j], (char*)V_lds + ((wv - 4) * 4 + j) * 1024);
    };

    stageQ();
    stageK2(kbase);

    for (int t = 0; t <= ntile; t++) {
        int kv0 = kv_begin + t * 32;

        asm volatile("s_waitcnt vmcnt(0)" ::: "memory");
        fence_barrier();                        // B1: K(t), V(t-1) staged (+Q at t=0)
        __builtin_amdgcn_sched_barrier(0);

        // ================= PHASE A =================
        if (isS) {
            if (t < ntile) {
                // swapped QK^T: D[kv][q] = K x Q^T over k-half kb; 2 independent chains
                f32x16 sa = {}, sb = {};
                int ksw = (l31 & 15) << 4;                 // K row = l31
                int qrow = qg * 32 + l31;                  // Q row (output col)
                int qsw = (qrow & 15) << 4;
                const char* kbase2 = (const char*)K_lds + l31 * 1024;
                const char* qbase2 = (const char*)Q_lds + qrow * 1024;
                #pragma unroll
                for (int ks = 0; ks < 16; ks += 2) {
                    int off0 = kb * 512 + ks * 32 + hi * 16;
                    int off1 = off0 + 32;
                    bfx8 k0 = *(const bfx8*)(kbase2 + (off0 ^ ksw));
                    bfx8 q0 = *(const bfx8*)(qbase2 + (off0 ^ qsw));
                    bfx8 k1 = *(const bfx8*)(kbase2 + (off1 ^ ksw));
                    bfx8 q1 = *(const bfx8*)(qbase2 + (off1 ^ qsw));
                    sa = __builtin_amdgcn_mfma_f32_32x32x16_bf16(k0, q0, sa, 0, 0, 0);
                    sb = __builtin_amdgcn_mfma_f32_32x32x16_bf16(k1, q1, sb, 0, 0, 0);
                }
                // scale + causal mask -> bf16 Sp[kb][qrow][kv]
                char* spb = (char*)Sp_lds + kb * 4096 + qrow * 64;
                int spsw = (qrow & 3) << 4;
                #pragma unroll
                for (int a = 0; a < 4; a++) {
                    bfx4 ch;
                    #pragma unroll
                    for (int b = 0; b < 4; b++) {
                        int r = a * 4 + b;
                        int kvloc = b + 8 * a + 4 * hi;    // m74/m101 C-layout
                        float x = (sa[r] + sb[r]) * rscale;
                        if (kv0 + kvloc > R0 + qrow) x = -INFINITY;
                        ch[b] = (short)f2bf(x);
                    }
                    *(bfx4*)(spb + ((a * 16 + hi * 8) ^ spsw)) = ch;
                }
            }
        } else {
            if (t > 0) {
                // rescale by alpha(t-1) (skipped when all alpha==1), then PV(t-1)
                fx4 apv[2];
                apv[0] = *(const fx4*)&alpha_lds[ro * 32 + l4 * 4];
                apv[1] = *(const fx4*)&alpha_lds[ro * 32 + 16 + l4 * 4];
                bool need = !(apv[0][0] == 1.f && apv[0][1] == 1.f && apv[0][2] == 1.f && apv[0][3] == 1.f
                           && apv[1][0] == 1.f && apv[1][1] == 1.f && apv[1][2] == 1.f && apv[1][3] == 1.f);
                if (__any(need)) {
                    #pragma unroll
                    for (int m = 0; m < 2; m++)
                        #pragma unroll
                        for (int n = 0; n < 8; n++)
                            #pragma unroll
                            for (int r = 0; r < 4; r++)
                                acc[m][n][r] *= apv[m][r];
                }
                bfx8 pa[2];
                #pragma unroll
                for (int m = 0; m < 2; m++) {
                    int prow = ro * 32 + m * 16 + l15;
                    int pr = prow >> 1;
                    int ppg = (((prow & 1) << 2) | l4) ^ (pr & 7);
                    pa[m] = *(const bfx8*)((const char*)p_lds + pr * 128 + ppg * 16);
                }
                #pragma unroll
                for (int n = 0; n < 8; n++) {
                    int d = co * 128 + n * 16 + l15;
                    int vr = d >> 1;
                    int vpg = (((d & 1) << 2) | l4) ^ (vr & 7);
                    bfx8 vfr = *(const bfx8*)((const char*)V_lds + vr * 128 + vpg * 16);
                    acc[0][n] = __builtin_amdgcn_mfma_f32_16x16x32_bf16(pa[0], vfr, acc[0][n], 0, 0, 0);
                    acc[1][n] = __builtin_amdgcn_mfma_f32_16x16x32_bf16(pa[1], vfr, acc[1][n], 0, 0, 0);
                }
            }
        }
        if (t == ntile) break;

        asm volatile("s_waitcnt lgkmcnt(0)" ::: "memory");
        fence_barrier();                        // B2: Sp complete; K/V/P reads done
        __builtin_amdgcn_sched_barrier(0);

        // stage K(t+1) and V(t) — running bases, const per-lane offsets
        if (t + 1 < ntile) stageK2(kbase + (size_t)(t + 1) * 32 * (QKV_LD * 2));
        stageV2(vbase + (size_t)t * 64);

        // ================= PHASE B: softmax(t) on S-waves =================
        if (isS) {
            int soff = srow * 64 + (((lane & 3) * 16) ^ ((srow & 3) << 4));
            bfx8 s0 = *(const bfx8*)((const char*)Sp_lds + soff);
            bfx8 s1 = *(const bfx8*)((const char*)Sp_lds + 4096 + soff);
            float xv[8];
            float mx = -INFINITY;
            #pragma unroll
            for (int j = 0; j < 8; j++) {
                xv[j] = bf2f((unsigned short)s0[j]) + bf2f((unsigned short)s1[j]);
                mx = fmaxf(mx, xv[j]);
            }
            mx = fmaxf(mx, __shfl_xor(mx, 1));
            mx = fmaxf(mx, __shfl_xor(mx, 2));
            float al;
            if (__all(mx <= m_run)) {
                al = 1.f;                                   // defer-max: no new max anywhere
            } else {
                float mn = fmaxf(m_run, mx);
                float msafe = (mn == -INFINITY) ? 0.f : mn;
                al = __expf(m_run - msafe);                 // m_run=-inf -> 0
                m_run = mn;
            }
            float msafe2 = (m_run == -INFINITY) ? 0.f : m_run;
            if ((lane & 3) == 0) alpha_lds[srow] = al;
            float ps = 0.f;
            bfx8 pw;
            #pragma unroll
            for (int j = 0; j < 8; j++) {
                float p = __expf(xv[j] - msafe2);           // -inf -> 0
                pw[j] = (short)f2bf(p);
                ps += p;
            }
            // paired-row P write: row srow, chunk lane&3
            {
                int pr = srow >> 1;
                int ppg = (((srow & 1) << 2) | (lane & 3)) ^ (pr & 7);
                *(bfx8*)((char*)p_lds + pr * 128 + ppg * 16) = pw;
            }
            ps += __shfl_xor(ps, 1);
            ps += __shfl_xor(ps, 2);
            l_run = l_run * al + ps;
        }
    }

    // ---- epilogue ----
    if (!isS) {
        #pragma unroll
        for (int m = 0; m < 2; m++)
            #pragma unroll
            for (int n = 0; n < 8; n++)
                #pragma unroll
                for (int r = 0; r < 4; r++) {
                    int rowl = ro * 32 + m * 16 + l4 * 4 + r;
                    int col = co * 128 + n * 16 + l15;
                    opart[((size_t)bid * 64 + rowl) * DMODEL + col] = f2bf(acc[m][n][r]);
                }
    } else if ((lane & 3) == 0) {
        mbuf[(size_t)bid * 64 + srow] = m_run;
        lbuf[(size_t)bid * 64 + srow] = l_run;
    }
}

// ---------------- combine partials across KV chunks ----------------
__global__ __launch_bounds__(256) void combine2_kernel(
    const unsigned short* __restrict__ opart,
    const float* __restrict__ mbuf, const float* __restrict__ lbuf,
    unsigned short* __restrict__ attn, int CH)
{
    int tid = threadIdx.x;
    int row = blockIdx.x * 4 + (tid >> 6);
    int col = (tid & 63) * 8;
    int qi = row >> 6, rowl = row & 63;
    int nch = qi / CH + 1;
    float M = -INFINITY;
    for (int c = 0; c < nch; c++) {
        int pidx = 128 * c - CH * c * (c - 1) / 2 + (qi - CH * c);
        M = fmaxf(M, mbuf[(size_t)pidx * 64 + rowl]);
    }
    float L = 0.f;
    float accv[8] = {0.f,0.f,0.f,0.f,0.f,0.f,0.f,0.f};
    for (int c = 0; c < nch; c++) {
        int pidx = 128 * c - CH * c * (c - 1) / 2 + (qi - CH * c);
        float e = __expf(mbuf[(size_t)pidx * 64 + rowl] - M);
        L += lbuf[(size_t)pidx * 64 + rowl] * e;
        bfx8 v = *(const bfx8*)(opart + ((size_t)pidx * 64 + rowl) * DMODEL + col);
        #pragma unroll
        for (int j = 0; j < 8; j++) accv[j] += e * bf2f((unsigned short)v[j]);
    }
    float invL = 1.0f / L;
    bfx8 o;
    #pragma unroll
    for (int j = 0; j < 8; j++) o[j] = f2bf(accv[j] * invL);
    *(bfx8*)(attn + (size_t)row * DMODEL + col) = o;
}

// ---------------- host launcher ----------------
extern "C" void kernel_launch(void* const* d_in, const int* in_sizes, int n_in,
                              void* d_out, int out_size, void* d_ws, size_t ws_size,
                              hipStream_t stream) {
    const float* h   = (const float*)d_in[0];
    const float* lnw = (const float*)d_in[1];
    const float* lnb = (const float*)d_in[2];
    const float* wq  = (const float*)d_in[3];
    const float* wk  = (const float*)d_in[4];
    const float* wv  = (const float*)d_in[5];
    const float* wo  = (const float*)d_in[6];
    float* out = (float*)d_out;

    char* ws = (char*)d_ws;
    size_t off = 0;
    auto alloc = [&](size_t bytes) {
        char* p = ws + off;
        off += (bytes + 255) & ~(size_t)255;
        return p;
    };
    const size_t TD2 = (size_t)T_SEQ * DMODEL * 2;
    const size_t W2  = (size_t)DMODEL * DMODEL * 2;
    unsigned short* hn   = (unsigned short*)alloc(TD2);
    unsigned short* wall = (unsigned short*)alloc(4 * W2);   // [wq;wk;wv;wo] contiguous
    unsigned short* wqkv = wall;
    unsigned short* wob  = wall + 3 * DMODEL * DMODEL;
    unsigned short* qkvb = (unsigned short*)alloc((size_t)T_SEQ * QKV_LD * 2);  // fused QKV
    unsigned short* vtb  = (unsigned short*)alloc(TD2);
    unsigned short* attnb= (unsigned short*)alloc(TD2);

    // KV chunking: CH kv-units (64 rows each) per chunk; NBLK = sum ceil((qi+1)/CH)
    int CH = 8, NBLK = 1088;     // 8*(1+..+16) = 1088, %8==0
    {
        size_t need = off + 2 * ((1088u * 64 * 4 + 255) & ~(size_t)255)
                    + (((size_t)1088 * 64 * 512 * 2 + 255) & ~(size_t)255);
        if (need > ws_size) { CH = 16; NBLK = 576; }   // 16*(1+..+8)=576, %8==0
    }
    float* mbuf = (float*)alloc((size_t)NBLK * 64 * 4);
    float* lbuf = (float*)alloc((size_t)NBLK * 64 * 4);
    unsigned short* opart = (unsigned short*)alloc((size_t)NBLK * 64 * 512 * 2);

    cvt4_bf16_kernel<<<dim3(512), dim3(256), 0, stream>>>(wq, wk, wv, wo, wall);

    layernorm_kernel<<<dim3(T_SEQ / 4), dim3(256), 0, stream>>>(h, lnw, lnb, hn);

    // fused QKV projection: [T,512] @ [1536,512]^T -> [T,1536]
    gemm_bt_kernel<0><<<dim3(QKV_LD / 128, T_SEQ / 128), dim3(256), 0, stream>>>(
        hn, wqkv, qkvb, nullptr, nullptr, T_SEQ, QKV_LD, DMODEL);

    // V (cols 1024..1535 of qkvb) -> Vt [512][T]
    transpose_kernel<<<dim3(T_SEQ / 64, DMODEL / 64), dim3(256), 0, stream>>>(
        qkvb + 2 * DMODEL, vtb, QKV_LD);

    flash17_kernel<<<dim3(NBLK), dim3(768), 0, stream>>>(
        qkvb, qkvb + DMODEL, vtb, opart, mbuf, lbuf, CH, NBLK);

    combine2_kernel<<<dim3(T_SEQ / 4), dim3(256), 0, stream>>>(opart, mbuf, lbuf, attnb, CH);

    gemm_bt_kernel<1><<<dim3(DMODEL / 128, T_SEQ / 128), dim3(256), 0, stream>>>(
        attnb, wob, nullptr, out, h, T_SEQ, DMODEL, DMODEL);
}

// Round 18
// 257.064 us; speedup vs baseline: 1.5390x; 1.0575x over previous
//
#include <hip/hip_runtime.h>
#include <stdint.h>

#define T_SEQ 8192
#define DMODEL 512
#define QKV_LD 1536   // row stride (elements) of fused QKV output

typedef __attribute__((ext_vector_type(8))) short bfx8;     // 8 bf16 = 4 VGPR
typedef __attribute__((ext_vector_type(4))) short bfx4;     // 4 bf16 = 2 VGPR
typedef __attribute__((ext_vector_type(4))) float fx4;      // 16x16 MFMA acc
typedef __attribute__((ext_vector_type(16))) float f32x16;  // 32x32 MFMA acc

__device__ __forceinline__ unsigned short f2bf(float f) {
    uint32_t u = __float_as_uint(f);
    u += 0x7fffu + ((u >> 16) & 1u);     // round-to-nearest-even (inf-safe)
    return (unsigned short)(u >> 16);
}
__device__ __forceinline__ float bf2f(unsigned short s) {
    return __uint_as_float(((uint32_t)s) << 16);
}

// async global->LDS, 16B per lane; LDS dest is wave-uniform base + lane*16 (HW)
__device__ __forceinline__ void gload16(const void* g, void* l) {
    __builtin_amdgcn_global_load_lds(
        (const __attribute__((address_space(1))) unsigned int*)g,
        (__attribute__((address_space(3))) unsigned int*)l,
        16, 0, 0);
}

__device__ __forceinline__ void fence_barrier() {
    asm volatile("" ::: "memory");
    __builtin_amdgcn_s_barrier();
    asm volatile("" ::: "memory");
}

// ---------------- weight conversion f32 -> bf16, all 4 weights in one launch ----------------
__global__ __launch_bounds__(256) void cvt4_bf16_kernel(const float* __restrict__ w0,
                                                        const float* __restrict__ w1,
                                                        const float* __restrict__ w2,
                                                        const float* __restrict__ w3,
                                                        unsigned short* __restrict__ dst) {
    int i = (blockIdx.x * 256 + threadIdx.x) * 8;          // 0 .. 4*262144-1
    int sel = i >> 18;                                     // 262144 elems per weight
    int off = i & 0x3FFFF;
    const float* src = (sel == 0) ? w0 : (sel == 1) ? w1 : (sel == 2) ? w2 : w3;
    fx4 a = *(const fx4*)(src + off);
    fx4 b = *(const fx4*)(src + off + 4);
    bfx8 o;
    o[0] = f2bf(a[0]); o[1] = f2bf(a[1]); o[2] = f2bf(a[2]); o[3] = f2bf(a[3]);
    o[4] = f2bf(b[0]); o[5] = f2bf(b[1]); o[6] = f2bf(b[2]); o[7] = f2bf(b[3]);
    *(bfx8*)(dst + i) = o;
}

// ---------------- LayerNorm (one wave per row) ----------------
__global__ __launch_bounds__(256) void layernorm_kernel(const float* __restrict__ h,
                                                        const float* __restrict__ w,
                                                        const float* __restrict__ b,
                                                        unsigned short* __restrict__ out) {
    int wv = threadIdx.x >> 6, lane = threadIdx.x & 63;
    int row = blockIdx.x * 4 + wv;
    const float* hr = h + (size_t)row * DMODEL + lane * 8;
    fx4 x0 = *(const fx4*)hr;
    fx4 x1 = *(const fx4*)(hr + 4);
    float s  = x0[0]+x0[1]+x0[2]+x0[3]+x1[0]+x1[1]+x1[2]+x1[3];
    float ss = x0[0]*x0[0]+x0[1]*x0[1]+x0[2]*x0[2]+x0[3]*x0[3]
             + x1[0]*x1[0]+x1[1]*x1[1]+x1[2]*x1[2]+x1[3]*x1[3];
    #pragma unroll
    for (int m = 1; m < 64; m <<= 1) { s += __shfl_xor(s, m); ss += __shfl_xor(ss, m); }
    float mu  = s * (1.0f / DMODEL);
    float var = ss * (1.0f / DMODEL) - mu * mu;
    float r = rsqrtf(var + 1e-5f);
    const float* wp = w + lane * 8; const float* bp = b + lane * 8;
    fx4 w0 = *(const fx4*)wp, w1 = *(const fx4*)(wp + 4);
    fx4 b0 = *(const fx4*)bp, b1 = *(const fx4*)(bp + 4);
    bfx8 o;
    o[0] = f2bf((x0[0]-mu)*r*w0[0] + b0[0]);
    o[1] = f2bf((x0[1]-mu)*r*w0[1] + b0[1]);
    o[2] = f2bf((x0[2]-mu)*r*w0[2] + b0[2]);
    o[3] = f2bf((x0[3]-mu)*r*w0[3] + b0[3]);
    o[4] = f2bf((x1[0]-mu)*r*w1[0] + b1[0]);
    o[5] = f2bf((x1[1]-mu)*r*w1[1] + b1[1]);
    o[6] = f2bf((x1[2]-mu)*r*w1[2] + b1[2]);
    o[7] = f2bf((x1[3]-mu)*r*w1[3] + b1[3]);
    *(bfx8*)(out + (size_t)row * DMODEL + lane * 8) = o;
}

// ---------------- C = A @ B^T  (both [rows][K] bf16), 128x128 tile ----------------
// R18: staging switched from reg-staged ds_write to global_load_lds width=16
// (m151: 874 vs 646 TF at 128^2 tiles). Linear LDS dest (wave-uniform base +
// lane*16), pre-swizzled per-lane global source; read side unchanged.
template<int RESID>
__global__ __launch_bounds__(256, 2) void gemm_bt_kernel(
    const unsigned short* __restrict__ A,   // [M][K]
    const unsigned short* __restrict__ B,   // [N][K]
    unsigned short* __restrict__ Cb,
    float* __restrict__ Cf,
    const float* __restrict__ resid,
    int M, int N, int K)
{
    __shared__ unsigned short At[128 * 64];
    __shared__ unsigned short Bt[128 * 64];
    int tid = threadIdx.x;
    int wv = tid >> 6, lane = tid & 63, l15 = lane & 15, l4 = lane >> 4;
    int wr = wv >> 1, wc = wv & 1;
    int row0 = blockIdx.y * 128;
    int col0 = blockIdx.x * 128;
    fx4 acc[4][4] = {};
    const char* Abase = (const char*)(A + (size_t)row0 * K);
    const char* Bbase = (const char*)(B + (size_t)col0 * K);

    // per-lane staging offsets (loop-invariant): LDS byte bix holds global
    // byte (bix&127)^((r&7)<<4) of tile-row r = bix>>7
    uint32_t soff[4];
    #pragma unroll
    for (int ch = 0; ch < 4; ch++) {
        int bix = (ch * 256 + tid) * 16;
        int r = bix >> 7;
        soff[ch] = (uint32_t)r * (K * 2) + (uint32_t)((bix & 127) ^ ((r & 7) << 4));
    }

    for (int kt = 0; kt < K; kt += 64) {
        const char* Asrc = Abase + kt * 2;
        const char* Bsrc = Bbase + kt * 2;
        #pragma unroll
        for (int ch = 0; ch < 4; ch++) {
            gload16(Asrc + soff[ch], (char*)At + ch * 4096 + wv * 1024);
            gload16(Bsrc + soff[ch], (char*)Bt + ch * 4096 + wv * 1024);
        }
        asm volatile("s_waitcnt vmcnt(0)" ::: "memory");
        __syncthreads();
        #pragma unroll
        for (int ks = 0; ks < 2; ks++) {
            bfx8 af[4], bf[4];
            #pragma unroll
            for (int m = 0; m < 4; m++) {
                int ra = wr * 64 + m * 16 + l15;
                int ka = (ks * 64 + l4 * 16) ^ ((ra & 7) << 4);
                af[m] = *(const bfx8*)((const char*)At + ra * 128 + ka);
                int rb = wc * 64 + m * 16 + l15;
                int kb = (ks * 64 + l4 * 16) ^ ((rb & 7) << 4);
                bf[m] = *(const bfx8*)((const char*)Bt + rb * 128 + kb);
            }
            #pragma unroll
            for (int m = 0; m < 4; m++)
                #pragma unroll
                for (int n = 0; n < 4; n++)
                    acc[m][n] = __builtin_amdgcn_mfma_f32_16x16x32_bf16(af[m], bf[n], acc[m][n], 0, 0, 0);
        }
        __syncthreads();
    }
    #pragma unroll
    for (int m = 0; m < 4; m++)
        #pragma unroll
        for (int n = 0; n < 4; n++)
            #pragma unroll
            for (int r = 0; r < 4; r++) {
                int row = row0 + wr * 64 + m * 16 + l4 * 4 + r;
                int col = col0 + wc * 64 + n * 16 + l15;
                float v = acc[m][n][r];
                size_t o = (size_t)row * N + col;
                if (RESID) Cf[o] = v + resid[o];
                else       Cb[o] = f2bf(v);
            }
}

// ---------------- transpose V [T][ld] -> Vt [D][T] ----------------
__global__ __launch_bounds__(256) void transpose_kernel(const unsigned short* __restrict__ v,
                                                        unsigned short* __restrict__ vt, int ld) {
    __shared__ unsigned short tile[64][80];
    int t = threadIdx.x;
    int r0 = blockIdx.x * 64;   // T dim
    int c0 = blockIdx.y * 64;   // D dim
    int r = t >> 2, cw = (t & 3) * 16;
    const unsigned short* src = v + (size_t)(r0 + r) * ld + c0 + cw;
    bfx8 a = *(const bfx8*)src;
    bfx8 b = *(const bfx8*)(src + 8);
    #pragma unroll
    for (int j = 0; j < 8; j++) { tile[r][cw + j] = a[j]; tile[r][cw + 8 + j] = b[j]; }
    __syncthreads();
    int dc = t >> 2, rb = (t & 3) * 16;
    bfx8 o0, o1;
    #pragma unroll
    for (int j = 0; j < 8; j++) { o0[j] = tile[rb + j][dc]; o1[j] = tile[rb + 8 + j][dc]; }
    unsigned short* dst = vt + (size_t)(c0 + dc) * T_SEQ + r0 + rb;
    *(bfx8*)dst = o0;
    *(bfx8*)(dst + 8) = o1;
}

// ---------------- flash attention v15 (EXACT R15 revert — verified 198us, no spills).
// R16 (Q-in-reg dbuf) and R17 (+16 AGPR chain split) both spilled; this register
// balance is saturated: any addition (arch OR agpr) spills. Structure plateau.
// 768 threads, 12 waves. QBLK=64, KVBLK=32.
// Waves 0-3 (S): swapped 32x32 QK^T k-split -> Sp bf16 -> softmax (phase B).
// Waves 4-11 (O, acc 64 AGPR): rescale+PV(t-1) in phase A, concurrent with QK^T(t).
// V/P macro-row pairing swizzle (2-way banks), strength-reduced staging, defer-max.
__global__ __launch_bounds__(768)
void flash15_kernel(
    const unsigned short* __restrict__ q,      // rows stride QKV_LD
    const unsigned short* __restrict__ k,      // rows stride QKV_LD
    const unsigned short* __restrict__ vt,     // [DMODEL][T_SEQ]
    unsigned short* __restrict__ opart,        // [NBLK][64][512] bf16 unnormalized
    float* __restrict__ mbuf, float* __restrict__ lbuf,   // [NBLK][64]
    int CH, int NBLK)                          // CH = kv chunks of 64-row units
{
    __shared__ unsigned short Q_lds[64 * 512];     // 64KB, rows 1024B
    __shared__ unsigned short K_lds[32 * 512];     // 32KB, rows 1024B
    __shared__ unsigned short V_lds[512 * 32];     // 32KB, 256 macro-rows of 128B
    __shared__ unsigned short Sp_lds[2 * 64 * 32]; // 8KB partial S bf16, rows 64B
    __shared__ unsigned short p_lds[64 * 32];      // 4KB, 32 macro-rows of 128B
    __shared__ float alpha_lds[64];

    int tid = threadIdx.x;
    int wv = tid >> 6, lane = tid & 63, l15 = lane & 15, l4 = lane >> 4;
    int l31 = lane & 31, hi = lane >> 5;
    bool isS = wv < 4;

    // XCD-chunked bijective swizzle (NBLK % 8 == 0)
    int L = blockIdx.x;
    int bid = (L & 7) * (NBLK >> 3) + (L >> 3);

    // chunk-major decode (128 q-tiles of 64 rows): cum(c) = 128c - CH*c*(c-1)/2
    int c = 0;
    while (bid >= 128 * (c + 1) - CH * (c + 1) * c / 2) c++;
    int qi = CH * c + (bid - (128 * c - CH * c * (c - 1) / 2));
    int R0 = qi * 64;
    int kv_begin = c * CH * 64;
    int kv_end = min(kv_begin + CH * 64, R0 + 64);
    int ntile = (kv_end - kv_begin) >> 5;       // 32-row kv tiles

    int qg = wv >> 1, kb = wv & 1;              // S roles (wv 0..3)
    int ro = (wv - 4) >> 2, co = (wv - 4) & 3;  // O roles (wv 4..11)

    const float rscale = 0.044194173824159216f; // 1/sqrt(512)

    float m_run = -INFINITY, l_run = 0.f;
    int srow = wv * 16 + (lane >> 2);           // S-wave softmax row (wv<4)
    fx4 acc[2][8] = {};                         // O-wave accumulator (AGPR)

    // ---- precomputed per-lane staging offsets (loop-invariant) ----
    uint32_t koff[4], voff[4];                  // K: waves 0-7; V: waves 4-11
    {
        #pragma unroll
        for (int j = 0; j < 4; j++) {
            int krow = wv * 4 + j;              // valid for wv<8
            koff[j] = (uint32_t)krow * (QKV_LD * 2) + ((lane * 16) ^ ((krow & 15) << 4));
            // V pairing: LDS byte = seg*1024 + lane*16; macro-row r, phys granule pg
            int seg = (wv - 4) * 4 + j;         // valid for wv>=4
            int r = seg * 8 + (lane >> 3);      // 128B macro-row (= d>>1)
            int pg = lane & 7;
            int lg = pg ^ (r & 7);              // logical granule
            int d = 2 * r + ((lg >> 2) & 1);    // V d-row
            int ch = lg & 3;                    // kv 16B chunk
            voff[j] = (uint32_t)d * (T_SEQ * 2) + ch * 16;
        }
    }
    const char* kbase = (const char*)k + (size_t)kv_begin * (QKV_LD * 2);  // advances 32 rows/iter
    const char* vbase = (const char*)vt + (size_t)kv_begin * 2;            // advances 64 B/iter

    auto stageQ = [&]() {
        if (wv >= 8) return;
        const char* qb = (const char*)q + (size_t)R0 * (QKV_LD * 2);
        #pragma unroll
        for (int j = 0; j < 8; j++) {
            int row = wv * 8 + j;
            const char* gp = qb + (size_t)row * (QKV_LD * 2)
                           + ((lane * 16) ^ ((row & 15) << 4));
            gload16(gp, (char*)Q_lds + row * 1024);
        }
    };
    auto stageK2 = [&](const char* kb2) {
        if (wv >= 8) return;                    // waves 0-7: 4 rows each
        #pragma unroll
        for (int j = 0; j < 4; j++)
            gload16(kb2 + koff[j], (char*)K_lds + (wv * 4 + j) * 1024);
    };
    auto stageV2 = [&](const char* vb2) {
        if (wv < 4) return;                     // waves 4-11: 4 segs each
        #pragma unroll
        for (int j = 0; j < 4; j++)
            gload16(vb2 + voff[j], (char*)V_lds + ((wv - 4) * 4 + j) * 1024);
    };

    stageQ();
    stageK2(kbase);

    for (int t = 0; t <= ntile; t++) {
        int kv0 = kv_begin + t * 32;

        asm volatile("s_waitcnt vmcnt(0)" ::: "memory");
        fence_barrier();                        // B1: K(t), V(t-1) staged (+Q at t=0)
        __builtin_amdgcn_sched_barrier(0);

        // ================= PHASE A =================
        if (isS) {
            if (t < ntile) {
                // swapped QK^T: D[kv][q] = K x Q^T over k-half kb
                f32x16 sacc = {};
                int ksw = (l31 & 15) << 4;                 // K row = l31
                int qrow = qg * 32 + l31;                  // Q row (output col)
                int qsw = (qrow & 15) << 4;
                const char* kbase2 = (const char*)K_lds + l31 * 1024;
                const char* qbase2 = (const char*)Q_lds + qrow * 1024;
                #pragma unroll
                for (int ks = 0; ks < 16; ks++) {
                    int off = kb * 512 + ks * 32 + hi * 16;
                    bfx8 kfr = *(const bfx8*)(kbase2 + (off ^ ksw));
                    bfx8 qfr = *(const bfx8*)(qbase2 + (off ^ qsw));
                    sacc = __builtin_amdgcn_mfma_f32_32x32x16_bf16(kfr, qfr, sacc, 0, 0, 0);
                }
                // scale + causal mask -> bf16 Sp[kb][qrow][kv]
                char* spb = (char*)Sp_lds + kb * 4096 + qrow * 64;
                int spsw = (qrow & 3) << 4;
                #pragma unroll
                for (int a = 0; a < 4; a++) {
                    bfx4 ch;
                    #pragma unroll
                    for (int b = 0; b < 4; b++) {
                        int r = a * 4 + b;
                        int kvloc = b + 8 * a + 4 * hi;    // m74/m101 C-layout
                        float x = sacc[r] * rscale;
                        if (kv0 + kvloc > R0 + qrow) x = -INFINITY;
                        ch[b] = (short)f2bf(x);
                    }
                    *(bfx4*)(spb + ((a * 16 + hi * 8) ^ spsw)) = ch;
                }
            }
        } else {
            if (t > 0) {
                // rescale by alpha(t-1) (skipped when all alpha==1), then PV(t-1)
                fx4 apv[2];
                apv[0] = *(const fx4*)&alpha_lds[ro * 32 + l4 * 4];
                apv[1] = *(const fx4*)&alpha_lds[ro * 32 + 16 + l4 * 4];
                bool need = !(apv[0][0] == 1.f && apv[0][1] == 1.f && apv[0][2] == 1.f && apv[0][3] == 1.f
                           && apv[1][0] == 1.f && apv[1][1] == 1.f && apv[1][2] == 1.f && apv[1][3] == 1.f);
                if (__any(need)) {
                    #pragma unroll
                    for (int m = 0; m < 2; m++)
                        #pragma unroll
                        for (int n = 0; n < 8; n++)
                            #pragma unroll
                            for (int r = 0; r < 4; r++)
                                acc[m][n][r] *= apv[m][r];
                }
                bfx8 pa[2];
                #pragma unroll
                for (int m = 0; m < 2; m++) {
                    int prow = ro * 32 + m * 16 + l15;
                    int pr = prow >> 1;
                    int ppg = (((prow & 1) << 2) | l4) ^ (pr & 7);
                    pa[m] = *(const bfx8*)((const char*)p_lds + pr * 128 + ppg * 16);
                }
                #pragma unroll
                for (int n = 0; n < 8; n++) {
                    int d = co * 128 + n * 16 + l15;
                    int vr = d >> 1;
                    int vpg = (((d & 1) << 2) | l4) ^ (vr & 7);
                    bfx8 vfr = *(const bfx8*)((const char*)V_lds + vr * 128 + vpg * 16);
                    acc[0][n] = __builtin_amdgcn_mfma_f32_16x16x32_bf16(pa[0], vfr, acc[0][n], 0, 0, 0);
                    acc[1][n] = __builtin_amdgcn_mfma_f32_16x16x32_bf16(pa[1], vfr, acc[1][n], 0, 0, 0);
                }
            }
        }
        if (t == ntile) break;

        asm volatile("s_waitcnt lgkmcnt(0)" ::: "memory");
        fence_barrier();                        // B2: Sp complete; K/V/P reads done
        __builtin_amdgcn_sched_barrier(0);

        // stage K(t+1) and V(t) — running bases, const per-lane offsets
        if (t + 1 < ntile) stageK2(kbase + (size_t)(t + 1) * 32 * (QKV_LD * 2));
        stageV2(vbase + (size_t)t * 64);

        // ================= PHASE B: softmax(t) on S-waves =================
        if (isS) {
            int soff = srow * 64 + (((lane & 3) * 16) ^ ((srow & 3) << 4));
            bfx8 s0 = *(const bfx8*)((const char*)Sp_lds + soff);
            bfx8 s1 = *(const bfx8*)((const char*)Sp_lds + 4096 + soff);
            float xv[8];
            float mx = -INFINITY;
            #pragma unroll
            for (int j = 0; j < 8; j++) {
                xv[j] = bf2f((unsigned short)s0[j]) + bf2f((unsigned short)s1[j]);
                mx = fmaxf(mx, xv[j]);
            }
            mx = fmaxf(mx, __shfl_xor(mx, 1));
            mx = fmaxf(mx, __shfl_xor(mx, 2));
            float al;
            if (__all(mx <= m_run)) {
                al = 1.f;                                   // defer-max: no new max anywhere
            } else {
                float mn = fmaxf(m_run, mx);
                float msafe = (mn == -INFINITY) ? 0.f : mn;
                al = __expf(m_run - msafe);                 // m_run=-inf -> 0
                m_run = mn;
            }
            float msafe2 = (m_run == -INFINITY) ? 0.f : m_run;
            if ((lane & 3) == 0) alpha_lds[srow] = al;
            float ps = 0.f;
            bfx8 pw;
            #pragma unroll
            for (int j = 0; j < 8; j++) {
                float p = __expf(xv[j] - msafe2);           // -inf -> 0
                pw[j] = (short)f2bf(p);
                ps += p;
            }
            // paired-row P write: row srow, chunk lane&3
            {
                int pr = srow >> 1;
                int ppg = (((srow & 1) << 2) | (lane & 3)) ^ (pr & 7);
                *(bfx8*)((char*)p_lds + pr * 128 + ppg * 16) = pw;
            }
            ps += __shfl_xor(ps, 1);
            ps += __shfl_xor(ps, 2);
            l_run = l_run * al + ps;
        }
    }

    // ---- epilogue ----
    if (!isS) {
        #pragma unroll
        for (int m = 0; m < 2; m++)
            #pragma unroll
            for (int n = 0; n < 8; n++)
                #pragma unroll
                for (int r = 0; r < 4; r++) {
                    int rowl = ro * 32 + m * 16 + l4 * 4 + r;
                    int col = co * 128 + n * 16 + l15;
                    opart[((size_t)bid * 64 + rowl) * DMODEL + col] = f2bf(acc[m][n][r]);
                }
    } else if ((lane & 3) == 0) {
        mbuf[(size_t)bid * 64 + srow] = m_run;
        lbuf[(size_t)bid * 64 + srow] = l_run;
    }
}

// ---------------- combine partials across KV chunks ----------------
__global__ __launch_bounds__(256) void combine2_kernel(
    const unsigned short* __restrict__ opart,
    const float* __restrict__ mbuf, const float* __restrict__ lbuf,
    unsigned short* __restrict__ attn, int CH)
{
    int tid = threadIdx.x;
    int row = blockIdx.x * 4 + (tid >> 6);
    int col = (tid & 63) * 8;
    int qi = row >> 6, rowl = row & 63;
    int nch = qi / CH + 1;
    float M = -INFINITY;
    for (int c = 0; c < nch; c++) {
        int pidx = 128 * c - CH * c * (c - 1) / 2 + (qi - CH * c);
        M = fmaxf(M, mbuf[(size_t)pidx * 64 + rowl]);
    }
    float L = 0.f;
    float accv[8] = {0.f,0.f,0.f,0.f,0.f,0.f,0.f,0.f};
    for (int c = 0; c < nch; c++) {
        int pidx = 128 * c - CH * c * (c - 1) / 2 + (qi - CH * c);
        float e = __expf(mbuf[(size_t)pidx * 64 + rowl] - M);
        L += lbuf[(size_t)pidx * 64 + rowl] * e;
        bfx8 v = *(const bfx8*)(opart + ((size_t)pidx * 64 + rowl) * DMODEL + col);
        #pragma unroll
        for (int j = 0; j < 8; j++) accv[j] += e * bf2f((unsigned short)v[j]);
    }
    float invL = 1.0f / L;
    bfx8 o;
    #pragma unroll
    for (int j = 0; j < 8; j++) o[j] = f2bf(accv[j] * invL);
    *(bfx8*)(attn + (size_t)row * DMODEL + col) = o;
}

// ---------------- host launcher ----------------
extern "C" void kernel_launch(void* const* d_in, const int* in_sizes, int n_in,
                              void* d_out, int out_size, void* d_ws, size_t ws_size,
                              hipStream_t stream) {
    const float* h   = (const float*)d_in[0];
    const float* lnw = (const float*)d_in[1];
    const float* lnb = (const float*)d_in[2];
    const float* wq  = (const float*)d_in[3];
    const float* wk  = (const float*)d_in[4];
    const float* wv  = (const float*)d_in[5];
    const float* wo  = (const float*)d_in[6];
    float* out = (float*)d_out;

    char* ws = (char*)d_ws;
    size_t off = 0;
    auto alloc = [&](size_t bytes) {
        char* p = ws + off;
        off += (bytes + 255) & ~(size_t)255;
        return p;
    };
    const size_t TD2 = (size_t)T_SEQ * DMODEL * 2;
    const size_t W2  = (size_t)DMODEL * DMODEL * 2;
    unsigned short* hn   = (unsigned short*)alloc(TD2);
    unsigned short* wall = (unsigned short*)alloc(4 * W2);   // [wq;wk;wv;wo] contiguous
    unsigned short* wqkv = wall;
    unsigned short* wob  = wall + 3 * DMODEL * DMODEL;
    unsigned short* qkvb = (unsigned short*)alloc((size_t)T_SEQ * QKV_LD * 2);  // fused QKV
    unsigned short* vtb  = (unsigned short*)alloc(TD2);
    unsigned short* attnb= (unsigned short*)alloc(TD2);

    // KV chunking: CH kv-units (64 rows each) per chunk; NBLK = sum ceil((qi+1)/CH)
    int CH = 8, NBLK = 1088;     // 8*(1+..+16) = 1088, %8==0
    {
        size_t need = off + 2 * ((1088u * 64 * 4 + 255) & ~(size_t)255)
                    + (((size_t)1088 * 64 * 512 * 2 + 255) & ~(size_t)255);
        if (need > ws_size) { CH = 16; NBLK = 576; }   // 16*(1+..+8)=576, %8==0
    }
    float* mbuf = (float*)alloc((size_t)NBLK * 64 * 4);
    float* lbuf = (float*)alloc((size_t)NBLK * 64 * 4);
    unsigned short* opart = (unsigned short*)alloc((size_t)NBLK * 64 * 512 * 2);

    cvt4_bf16_kernel<<<dim3(512), dim3(256), 0, stream>>>(wq, wk, wv, wo, wall);

    layernorm_kernel<<<dim3(T_SEQ / 4), dim3(256), 0, stream>>>(h, lnw, lnb, hn);

    // fused QKV projection: [T,512] @ [1536,512]^T -> [T,1536]
    gemm_bt_kernel<0><<<dim3(QKV_LD / 128, T_SEQ / 128), dim3(256), 0, stream>>>(
        hn, wqkv, qkvb, nullptr, nullptr, T_SEQ, QKV_LD, DMODEL);

    // V (cols 1024..1535 of qkvb) -> Vt [512][T]
    transpose_kernel<<<dim3(T_SEQ / 64, DMODEL / 64), dim3(256), 0, stream>>>(
        qkvb + 2 * DMODEL, vtb, QKV_LD);

    flash15_kernel<<<dim3(NBLK), dim3(768), 0, stream>>>(
        qkvb, qkvb + DMODEL, vtb, opart, mbuf, lbuf, CH, NBLK);

    combine2_kernel<<<dim3(T_SEQ / 4), dim3(256), 0, stream>>>(opart, mbuf, lbuf, attnb, CH);

    gemm_bt_kernel<1><<<dim3(DMODEL / 128, T_SEQ / 128), dim3(256), 0, stream>>>(
        attnb, wob, nullptr, out, h, T_SEQ, DMODEL, DMODEL);
}

// Round 19
// 250.378 us; speedup vs baseline: 1.5801x; 1.0267x over previous
//
#include <hip/hip_runtime.h>
#include <stdint.h>

#define T_SEQ 8192
#define DMODEL 512
#define QKV_LD 1536   // row stride (elements) of fused QKV output

typedef __attribute__((ext_vector_type(8))) short bfx8;     // 8 bf16 = 4 VGPR
typedef __attribute__((ext_vector_type(4))) short bfx4;     // 4 bf16 = 2 VGPR
typedef __attribute__((ext_vector_type(4))) float fx4;      // 16x16 MFMA acc
typedef __attribute__((ext_vector_type(16))) float f32x16;  // 32x32 MFMA acc

__device__ __forceinline__ unsigned short f2bf(float f) {
    uint32_t u = __float_as_uint(f);
    u += 0x7fffu + ((u >> 16) & 1u);     // round-to-nearest-even (inf-safe)
    return (unsigned short)(u >> 16);
}
__device__ __forceinline__ float bf2f(unsigned short s) {
    return __uint_as_float(((uint32_t)s) << 16);
}

// async global->LDS, 16B per lane; LDS dest is wave-uniform base + lane*16 (HW)
__device__ __forceinline__ void gload16(const void* g, void* l) {
    __builtin_amdgcn_global_load_lds(
        (const __attribute__((address_space(1))) unsigned int*)g,
        (__attribute__((address_space(3))) unsigned int*)l,
        16, 0, 0);
}

__device__ __forceinline__ void fence_barrier() {
    asm volatile("" ::: "memory");
    __builtin_amdgcn_s_barrier();
    asm volatile("" ::: "memory");
}

// ---------------- weight conversion f32 -> bf16, all 4 weights in one launch ----------------
__global__ __launch_bounds__(256) void cvt4_bf16_kernel(const float* __restrict__ w0,
                                                        const float* __restrict__ w1,
                                                        const float* __restrict__ w2,
                                                        const float* __restrict__ w3,
                                                        unsigned short* __restrict__ dst) {
    int i = (blockIdx.x * 256 + threadIdx.x) * 8;          // 0 .. 4*262144-1
    int sel = i >> 18;                                     // 262144 elems per weight
    int off = i & 0x3FFFF;
    const float* src = (sel == 0) ? w0 : (sel == 1) ? w1 : (sel == 2) ? w2 : w3;
    fx4 a = *(const fx4*)(src + off);
    fx4 b = *(const fx4*)(src + off + 4);
    bfx8 o;
    o[0] = f2bf(a[0]); o[1] = f2bf(a[1]); o[2] = f2bf(a[2]); o[3] = f2bf(a[3]);
    o[4] = f2bf(b[0]); o[5] = f2bf(b[1]); o[6] = f2bf(b[2]); o[7] = f2bf(b[3]);
    *(bfx8*)(dst + i) = o;
}

// ---------------- LayerNorm (one wave per row) ----------------
__global__ __launch_bounds__(256) void layernorm_kernel(const float* __restrict__ h,
                                                        const float* __restrict__ w,
                                                        const float* __restrict__ b,
                                                        unsigned short* __restrict__ out) {
    int wv = threadIdx.x >> 6, lane = threadIdx.x & 63;
    int row = blockIdx.x * 4 + wv;
    const float* hr = h + (size_t)row * DMODEL + lane * 8;
    fx4 x0 = *(const fx4*)hr;
    fx4 x1 = *(const fx4*)(hr + 4);
    float s  = x0[0]+x0[1]+x0[2]+x0[3]+x1[0]+x1[1]+x1[2]+x1[3];
    float ss = x0[0]*x0[0]+x0[1]*x0[1]+x0[2]*x0[2]+x0[3]*x0[3]
             + x1[0]*x1[0]+x1[1]*x1[1]+x1[2]*x1[2]+x1[3]*x1[3];
    #pragma unroll
    for (int m = 1; m < 64; m <<= 1) { s += __shfl_xor(s, m); ss += __shfl_xor(ss, m); }
    float mu  = s * (1.0f / DMODEL);
    float var = ss * (1.0f / DMODEL) - mu * mu;
    float r = rsqrtf(var + 1e-5f);
    const float* wp = w + lane * 8; const float* bp = b + lane * 8;
    fx4 w0 = *(const fx4*)wp, w1 = *(const fx4*)(wp + 4);
    fx4 b0 = *(const fx4*)bp, b1 = *(const fx4*)(bp + 4);
    bfx8 o;
    o[0] = f2bf((x0[0]-mu)*r*w0[0] + b0[0]);
    o[1] = f2bf((x0[1]-mu)*r*w0[1] + b0[1]);
    o[2] = f2bf((x0[2]-mu)*r*w0[2] + b0[2]);
    o[3] = f2bf((x0[3]-mu)*r*w0[3] + b0[3]);
    o[4] = f2bf((x1[0]-mu)*r*w1[0] + b1[0]);
    o[5] = f2bf((x1[1]-mu)*r*w1[1] + b1[1]);
    o[6] = f2bf((x1[2]-mu)*r*w1[2] + b1[2]);
    o[7] = f2bf((x1[3]-mu)*r*w1[3] + b1[3]);
    *(bfx8*)(out + (size_t)row * DMODEL + lane * 8) = o;
}

// ---------------- C = A @ B^T  (both [rows][K] bf16), 128x128 tile ----------------
template<int RESID>
__global__ __launch_bounds__(256, 2) void gemm_bt_kernel(
    const unsigned short* __restrict__ A,   // [M][K]
    const unsigned short* __restrict__ B,   // [N][K]
    unsigned short* __restrict__ Cb,
    float* __restrict__ Cf,
    const float* __restrict__ resid,
    int M, int N, int K)
{
    __shared__ unsigned short At[128 * 64];
    __shared__ unsigned short Bt[128 * 64];
    int tid = threadIdx.x;
    int wv = tid >> 6, lane = tid & 63, l15 = lane & 15, l4 = lane >> 4;
    int wr = wv >> 1, wc = wv & 1;
    int row0 = blockIdx.y * 128;
    int col0 = blockIdx.x * 128;
    fx4 acc[4][4] = {};
    const char* Abase = (const char*)(A + (size_t)row0 * K);
    const char* Bbase = (const char*)(B + (size_t)col0 * K);
    for (int kt = 0; kt < K; kt += 64) {
        #pragma unroll
        for (int ch = 0; ch < 4; ch++) {
            int bix = (ch * 256 + tid) * 16;
            int r = bix >> 7;
            int sb = (bix & 127) ^ ((r & 7) << 4);
            bfx8 va = *(const bfx8*)(Abase + (size_t)r * (K * 2) + kt * 2 + sb);
            bfx8 vb = *(const bfx8*)(Bbase + (size_t)r * (K * 2) + kt * 2 + sb);
            *(bfx8*)((char*)At + bix) = va;
            *(bfx8*)((char*)Bt + bix) = vb;
        }
        __syncthreads();
        #pragma unroll
        for (int ks = 0; ks < 2; ks++) {
            bfx8 af[4], bf[4];
            #pragma unroll
            for (int m = 0; m < 4; m++) {
                int ra = wr * 64 + m * 16 + l15;
                int ka = (ks * 64 + l4 * 16) ^ ((ra & 7) << 4);
                af[m] = *(const bfx8*)((const char*)At + ra * 128 + ka);
                int rb = wc * 64 + m * 16 + l15;
                int kb = (ks * 64 + l4 * 16) ^ ((rb & 7) << 4);
                bf[m] = *(const bfx8*)((const char*)Bt + rb * 128 + kb);
            }
            #pragma unroll
            for (int m = 0; m < 4; m++)
                #pragma unroll
                for (int n = 0; n < 4; n++)
                    acc[m][n] = __builtin_amdgcn_mfma_f32_16x16x32_bf16(af[m], bf[n], acc[m][n], 0, 0, 0);
        }
        __syncthreads();
    }
    #pragma unroll
    for (int m = 0; m < 4; m++)
        #pragma unroll
        for (int n = 0; n < 4; n++)
            #pragma unroll
            for (int r = 0; r < 4; r++) {
                int row = row0 + wr * 64 + m * 16 + l4 * 4 + r;
                int col = col0 + wc * 64 + n * 16 + l15;
                float v = acc[m][n][r];
                size_t o = (size_t)row * N + col;
                if (RESID) Cf[o] = v + resid[o];
                else       Cb[o] = f2bf(v);
            }
}

// ---------------- transpose V [T][ld] -> Vt [D][T] ----------------
__global__ __launch_bounds__(256) void transpose_kernel(const unsigned short* __restrict__ v,
                                                        unsigned short* __restrict__ vt, int ld) {
    __shared__ unsigned short tile[64][80];
    int t = threadIdx.x;
    int r0 = blockIdx.x * 64;   // T dim
    int c0 = blockIdx.y * 64;   // D dim
    int r = t >> 2, cw = (t & 3) * 16;
    const unsigned short* src = v + (size_t)(r0 + r) * ld + c0 + cw;
    bfx8 a = *(const bfx8*)src;
    bfx8 b = *(const bfx8*)(src + 8);
    #pragma unroll
    for (int j = 0; j < 8; j++) { tile[r][cw + j] = a[j]; tile[r][cw + 8 + j] = b[j]; }
    __syncthreads();
    int dc = t >> 2, rb = (t & 3) * 16;
    bfx8 o0, o1;
    #pragma unroll
    for (int j = 0; j < 8; j++) { o0[j] = tile[rb + j][dc]; o1[j] = tile[rb + 8 + j][dc]; }
    unsigned short* dst = vt + (size_t)(c0 + dc) * T_SEQ + r0 + rb;
    *(bfx8*)dst = o0;
    *(bfx8*)(dst + 8) = o1;
}

// ---------------- flash attention v15 (R15 verified best: 198us flash / 251 total).
// 768 threads, 12 waves. QBLK=64, KVBLK=32.
// Waves 0-3 (S): swapped 32x32 QK^T k-split -> Sp bf16 -> softmax (phase B).
// Waves 4-11 (O, acc 64 AGPR): rescale+PV(t-1) in phase A, concurrent with QK^T(t).
// V/P macro-row pairing swizzle (2-way banks), strength-reduced staging, defer-max.
// Register balance saturated (R16/R17: any addition, arch or AGPR, spills).
__global__ __launch_bounds__(768)
void flash15_kernel(
    const unsigned short* __restrict__ q,      // rows stride QKV_LD
    const unsigned short* __restrict__ k,      // rows stride QKV_LD
    const unsigned short* __restrict__ vt,     // [DMODEL][T_SEQ]
    unsigned short* __restrict__ opart,        // [NBLK][64][512] bf16 unnormalized
    float* __restrict__ mbuf, float* __restrict__ lbuf,   // [NBLK][64]
    int CH, int NBLK)                          // CH = kv chunks of 64-row units
{
    __shared__ unsigned short Q_lds[64 * 512];     // 64KB, rows 1024B
    __shared__ unsigned short K_lds[32 * 512];     // 32KB, rows 1024B
    __shared__ unsigned short V_lds[512 * 32];     // 32KB, 256 macro-rows of 128B
    __shared__ unsigned short Sp_lds[2 * 64 * 32]; // 8KB partial S bf16, rows 64B
    __shared__ unsigned short p_lds[64 * 32];      // 4KB, 32 macro-rows of 128B
    __shared__ float alpha_lds[64];

    int tid = threadIdx.x;
    int wv = tid >> 6, lane = tid & 63, l15 = lane & 15, l4 = lane >> 4;
    int l31 = lane & 31, hi = lane >> 5;
    bool isS = wv < 4;

    // XCD-chunked bijective swizzle (NBLK % 8 == 0)
    int L = blockIdx.x;
    int bid = (L & 7) * (NBLK >> 3) + (L >> 3);

    // chunk-major decode (128 q-tiles of 64 rows): cum(c) = 128c - CH*c*(c-1)/2
    int c = 0;
    while (bid >= 128 * (c + 1) - CH * (c + 1) * c / 2) c++;
    int qi = CH * c + (bid - (128 * c - CH * c * (c - 1) / 2));
    int R0 = qi * 64;
    int kv_begin = c * CH * 64;
    int kv_end = min(kv_begin + CH * 64, R0 + 64);
    int ntile = (kv_end - kv_begin) >> 5;       // 32-row kv tiles

    int qg = wv >> 1, kb = wv & 1;              // S roles (wv 0..3)
    int ro = (wv - 4) >> 2, co = (wv - 4) & 3;  // O roles (wv 4..11)

    const float rscale = 0.044194173824159216f; // 1/sqrt(512)

    float m_run = -INFINITY, l_run = 0.f;
    int srow = wv * 16 + (lane >> 2);           // S-wave softmax row (wv<4)
    fx4 acc[2][8] = {};                         // O-wave accumulator (AGPR)

    // ---- precomputed per-lane staging offsets (loop-invariant) ----
    uint32_t koff[4], voff[4];                  // K: waves 0-7; V: waves 4-11
    {
        #pragma unroll
        for (int j = 0; j < 4; j++) {
            int krow = wv * 4 + j;              // valid for wv<8
            koff[j] = (uint32_t)krow * (QKV_LD * 2) + ((lane * 16) ^ ((krow & 15) << 4));
            // V pairing: LDS byte = seg*1024 + lane*16; macro-row r, phys granule pg
            int seg = (wv - 4) * 4 + j;         // valid for wv>=4
            int r = seg * 8 + (lane >> 3);      // 128B macro-row (= d>>1)
            int pg = lane & 7;
            int lg = pg ^ (r & 7);              // logical granule
            int d = 2 * r + ((lg >> 2) & 1);    // V d-row
            int ch = lg & 3;                    // kv 16B chunk
            voff[j] = (uint32_t)d * (T_SEQ * 2) + ch * 16;
        }
    }
    const char* kbase = (const char*)k + (size_t)kv_begin * (QKV_LD * 2);  // advances 32 rows/iter
    const char* vbase = (const char*)vt + (size_t)kv_begin * 2;            // advances 64 B/iter

    auto stageQ = [&]() {
        if (wv >= 8) return;
        const char* qb = (const char*)q + (size_t)R0 * (QKV_LD * 2);
        #pragma unroll
        for (int j = 0; j < 8; j++) {
            int row = wv * 8 + j;
            const char* gp = qb + (size_t)row * (QKV_LD * 2)
                           + ((lane * 16) ^ ((row & 15) << 4));
            gload16(gp, (char*)Q_lds + row * 1024);
        }
    };
    auto stageK2 = [&](const char* kb2) {
        if (wv >= 8) return;                    // waves 0-7: 4 rows each
        #pragma unroll
        for (int j = 0; j < 4; j++)
            gload16(kb2 + koff[j], (char*)K_lds + (wv * 4 + j) * 1024);
    };
    auto stageV2 = [&](const char* vb2) {
        if (wv < 4) return;                     // waves 4-11: 4 segs each
        #pragma unroll
        for (int j = 0; j < 4; j++)
            gload16(vb2 + voff[j], (char*)V_lds + ((wv - 4) * 4 + j) * 1024);
    };

    stageQ();
    stageK2(kbase);

    for (int t = 0; t <= ntile; t++) {
        int kv0 = kv_begin + t * 32;

        asm volatile("s_waitcnt vmcnt(0)" ::: "memory");
        fence_barrier();                        // B1: K(t), V(t-1) staged (+Q at t=0)
        __builtin_amdgcn_sched_barrier(0);

        // ================= PHASE A =================
        if (isS) {
            if (t < ntile) {
                // swapped QK^T: D[kv][q] = K x Q^T over k-half kb
                f32x16 sacc = {};
                int ksw = (l31 & 15) << 4;                 // K row = l31
                int qrow = qg * 32 + l31;                  // Q row (output col)
                int qsw = (qrow & 15) << 4;
                const char* kbase2 = (const char*)K_lds + l31 * 1024;
                const char* qbase2 = (const char*)Q_lds + qrow * 1024;
                #pragma unroll
                for (int ks = 0; ks < 16; ks++) {
                    int off = kb * 512 + ks * 32 + hi * 16;
                    bfx8 kfr = *(const bfx8*)(kbase2 + (off ^ ksw));
                    bfx8 qfr = *(const bfx8*)(qbase2 + (off ^ qsw));
                    sacc = __builtin_amdgcn_mfma_f32_32x32x16_bf16(kfr, qfr, sacc, 0, 0, 0);
                }
                // scale + causal mask -> bf16 Sp[kb][qrow][kv]
                char* spb = (char*)Sp_lds + kb * 4096 + qrow * 64;
                int spsw = (qrow & 3) << 4;
                #pragma unroll
                for (int a = 0; a < 4; a++) {
                    bfx4 ch;
                    #pragma unroll
                    for (int b = 0; b < 4; b++) {
                        int r = a * 4 + b;
                        int kvloc = b + 8 * a + 4 * hi;    // m74/m101 C-layout
                        float x = sacc[r] * rscale;
                        if (kv0 + kvloc > R0 + qrow) x = -INFINITY;
                        ch[b] = (short)f2bf(x);
                    }
                    *(bfx4*)(spb + ((a * 16 + hi * 8) ^ spsw)) = ch;
                }
            }
        } else {
            if (t > 0) {
                // rescale by alpha(t-1) (skipped when all alpha==1), then PV(t-1)
                fx4 apv[2];
                apv[0] = *(const fx4*)&alpha_lds[ro * 32 + l4 * 4];
                apv[1] = *(const fx4*)&alpha_lds[ro * 32 + 16 + l4 * 4];
                bool need = !(apv[0][0] == 1.f && apv[0][1] == 1.f && apv[0][2] == 1.f && apv[0][3] == 1.f
                           && apv[1][0] == 1.f && apv[1][1] == 1.f && apv[1][2] == 1.f && apv[1][3] == 1.f);
                if (__any(need)) {
                    #pragma unroll
                    for (int m = 0; m < 2; m++)
                        #pragma unroll
                        for (int n = 0; n < 8; n++)
                            #pragma unroll
                            for (int r = 0; r < 4; r++)
                                acc[m][n][r] *= apv[m][r];
                }
                bfx8 pa[2];
                #pragma unroll
                for (int m = 0; m < 2; m++) {
                    int prow = ro * 32 + m * 16 + l15;
                    int pr = prow >> 1;
                    int ppg = (((prow & 1) << 2) | l4) ^ (pr & 7);
                    pa[m] = *(const bfx8*)((const char*)p_lds + pr * 128 + ppg * 16);
                }
                #pragma unroll
                for (int n = 0; n < 8; n++) {
                    int d = co * 128 + n * 16 + l15;
                    int vr = d >> 1;
                    int vpg = (((d & 1) << 2) | l4) ^ (vr & 7);
                    bfx8 vfr = *(const bfx8*)((const char*)V_lds + vr * 128 + vpg * 16);
                    acc[0][n] = __builtin_amdgcn_mfma_f32_16x16x32_bf16(pa[0], vfr, acc[0][n], 0, 0, 0);
                    acc[1][n] = __builtin_amdgcn_mfma_f32_16x16x32_bf16(pa[1], vfr, acc[1][n], 0, 0, 0);
                }
            }
        }
        if (t == ntile) break;

        asm volatile("s_waitcnt lgkmcnt(0)" ::: "memory");
        fence_barrier();                        // B2: Sp complete; K/V/P reads done
        __builtin_amdgcn_sched_barrier(0);

        // stage K(t+1) and V(t) — running bases, const per-lane offsets
        if (t + 1 < ntile) stageK2(kbase + (size_t)(t + 1) * 32 * (QKV_LD * 2));
        stageV2(vbase + (size_t)t * 64);

        // ================= PHASE B: softmax(t) on S-waves =================
        if (isS) {
            int soff = srow * 64 + (((lane & 3) * 16) ^ ((srow & 3) << 4));
            bfx8 s0 = *(const bfx8*)((const char*)Sp_lds + soff);
            bfx8 s1 = *(const bfx8*)((const char*)Sp_lds + 4096 + soff);
            float xv[8];
            float mx = -INFINITY;
            #pragma unroll
            for (int j = 0; j < 8; j++) {
                xv[j] = bf2f((unsigned short)s0[j]) + bf2f((unsigned short)s1[j]);
                mx = fmaxf(mx, xv[j]);
            }
            mx = fmaxf(mx, __shfl_xor(mx, 1));
            mx = fmaxf(mx, __shfl_xor(mx, 2));
            float al;
            if (__all(mx <= m_run)) {
                al = 1.f;                                   // defer-max: no new max anywhere
            } else {
                float mn = fmaxf(m_run, mx);
                float msafe = (mn == -INFINITY) ? 0.f : mn;
                al = __expf(m_run - msafe);                 // m_run=-inf -> 0
                m_run = mn;
            }
            float msafe2 = (m_run == -INFINITY) ? 0.f : m_run;
            if ((lane & 3) == 0) alpha_lds[srow] = al;
            float ps = 0.f;
            bfx8 pw;
            #pragma unroll
            for (int j = 0; j < 8; j++) {
                float p = __expf(xv[j] - msafe2);           // -inf -> 0
                pw[j] = (short)f2bf(p);
                ps += p;
            }
            // paired-row P write: row srow, chunk lane&3
            {
                int pr = srow >> 1;
                int ppg = (((srow & 1) << 2) | (lane & 3)) ^ (pr & 7);
                *(bfx8*)((char*)p_lds + pr * 128 + ppg * 16) = pw;
            }
            ps += __shfl_xor(ps, 1);
            ps += __shfl_xor(ps, 2);
            l_run = l_run * al + ps;
        }
    }

    // ---- epilogue ----
    if (!isS) {
        #pragma unroll
        for (int m = 0; m < 2; m++)
            #pragma unroll
            for (int n = 0; n < 8; n++)
                #pragma unroll
                for (int r = 0; r < 4; r++) {
                    int rowl = ro * 32 + m * 16 + l4 * 4 + r;
                    int col = co * 128 + n * 16 + l15;
                    opart[((size_t)bid * 64 + rowl) * DMODEL + col] = f2bf(acc[m][n][r]);
                }
    } else if ((lane & 3) == 0) {
        mbuf[(size_t)bid * 64 + srow] = m_run;
        lbuf[(size_t)bid * 64 + srow] = l_run;
    }
}

// ---------------- combine partials across KV chunks ----------------
__global__ __launch_bounds__(256) void combine2_kernel(
    const unsigned short* __restrict__ opart,
    const float* __restrict__ mbuf, const float* __restrict__ lbuf,
    unsigned short* __restrict__ attn, int CH)
{
    int tid = threadIdx.x;
    int row = blockIdx.x * 4 + (tid >> 6);
    int col = (tid & 63) * 8;
    int qi = row >> 6, rowl = row & 63;
    int nch = qi / CH + 1;
    float M = -INFINITY;
    for (int c = 0; c < nch; c++) {
        int pidx = 128 * c - CH * c * (c - 1) / 2 + (qi - CH * c);
        M = fmaxf(M, mbuf[(size_t)pidx * 64 + rowl]);
    }
    float L = 0.f;
    float accv[8] = {0.f,0.f,0.f,0.f,0.f,0.f,0.f,0.f};
    for (int c = 0; c < nch; c++) {
        int pidx = 128 * c - CH * c * (c - 1) / 2 + (qi - CH * c);
        float e = __expf(mbuf[(size_t)pidx * 64 + rowl] - M);
        L += lbuf[(size_t)pidx * 64 + rowl] * e;
        bfx8 v = *(const bfx8*)(opart + ((size_t)pidx * 64 + rowl) * DMODEL + col);
        #pragma unroll
        for (int j = 0; j < 8; j++) accv[j] += e * bf2f((unsigned short)v[j]);
    }
    float invL = 1.0f / L;
    bfx8 o;
    #pragma unroll
    for (int j = 0; j < 8; j++) o[j] = f2bf(accv[j] * invL);
    *(bfx8*)(attn + (size_t)row * DMODEL + col) = o;
}

// ---------------- host launcher ----------------
extern "C" void kernel_launch(void* const* d_in, const int* in_sizes, int n_in,
                              void* d_out, int out_size, void* d_ws, size_t ws_size,
                              hipStream_t stream) {
    const float* h   = (const float*)d_in[0];
    const float* lnw = (const float*)d_in[1];
    const float* lnb = (const float*)d_in[2];
    const float* wq  = (const float*)d_in[3];
    const float* wk  = (const float*)d_in[4];
    const float* wv  = (const float*)d_in[5];
    const float* wo  = (const float*)d_in[6];
    float* out = (float*)d_out;

    char* ws = (char*)d_ws;
    size_t off = 0;
    auto alloc = [&](size_t bytes) {
        char* p = ws + off;
        off += (bytes + 255) & ~(size_t)255;
        return p;
    };
    const size_t TD2 = (size_t)T_SEQ * DMODEL * 2;
    const size_t W2  = (size_t)DMODEL * DMODEL * 2;
    unsigned short* hn   = (unsigned short*)alloc(TD2);
    unsigned short* wall = (unsigned short*)alloc(4 * W2);   // [wq;wk;wv;wo] contiguous
    unsigned short* wqkv = wall;
    unsigned short* wob  = wall + 3 * DMODEL * DMODEL;
    unsigned short* qkvb = (unsigned short*)alloc((size_t)T_SEQ * QKV_LD * 2);  // fused QKV
    unsigned short* vtb  = (unsigned short*)alloc(TD2);
    unsigned short* attnb= (unsigned short*)alloc(TD2);

    // KV chunking: CH kv-units (64 rows each) per chunk; NBLK = sum ceil((qi+1)/CH)
    int CH = 8, NBLK = 1088;     // 8*(1+..+16) = 1088, %8==0
    {
        size_t need = off + 2 * ((1088u * 64 * 4 + 255) & ~(size_t)255)
                    + (((size_t)1088 * 64 * 512 * 2 + 255) & ~(size_t)255);
        if (need > ws_size) { CH = 16; NBLK = 576; }   // 16*(1+..+8)=576, %8==0
    }
    float* mbuf = (float*)alloc((size_t)NBLK * 64 * 4);
    float* lbuf = (float*)alloc((size_t)NBLK * 64 * 4);
    unsigned short* opart = (unsigned short*)alloc((size_t)NBLK * 64 * 512 * 2);

    cvt4_bf16_kernel<<<dim3(512), dim3(256), 0, stream>>>(wq, wk, wv, wo, wall);

    layernorm_kernel<<<dim3(T_SEQ / 4), dim3(256), 0, stream>>>(h, lnw, lnb, hn);

    // fused QKV projection: [T,512] @ [1536,512]^T -> [T,1536]
    gemm_bt_kernel<0><<<dim3(QKV_LD / 128, T_SEQ / 128), dim3(256), 0, stream>>>(
        hn, wqkv, qkvb, nullptr, nullptr, T_SEQ, QKV_LD, DMODEL);

    // V (cols 1024..1535 of qkvb) -> Vt [512][T]
    transpose_kernel<<<dim3(T_SEQ / 64, DMODEL / 64), dim3(256), 0, stream>>>(
        qkvb + 2 * DMODEL, vtb, QKV_LD);

    flash15_kernel<<<dim3(NBLK), dim3(768), 0, stream>>>(
        qkvb, qkvb + DMODEL, vtb, opart, mbuf, lbuf, CH, NBLK);

    combine2_kernel<<<dim3(T_SEQ / 4), dim3(256), 0, stream>>>(opart, mbuf, lbuf, attnb, CH);

    gemm_bt_kernel<1><<<dim3(DMODEL / 128, T_SEQ / 128), dim3(256), 0, stream>>>(
        attnb, wob, nullptr, out, h, T_SEQ, DMODEL, DMODEL);
}